// Round 2
// baseline (1401.396 us; speedup 1.0000x reference)
//
#include <hip/hip_runtime.h>
#include <hip/hip_bf16.h>
#include <cstdint>

// ---------- bf16 helpers (raw ushort representation) ----------
__device__ __forceinline__ unsigned short f2b(float f) {
    union { float f; unsigned int i; } v; v.f = f;
    unsigned int i = v.i;
    unsigned int r = (i + 0x7FFFu + ((i >> 16) & 1u)) >> 16;   // RNE, finite inputs
    return (unsigned short)r;
}
__device__ __forceinline__ float b2f_lo(unsigned int p) {
    union { unsigned int i; float f; } v; v.i = p << 16; return v.f;
}
__device__ __forceinline__ float b2f_hi(unsigned int p) {
    union { unsigned int i; float f; } v; v.i = p & 0xFFFF0000u; return v.f;
}
__device__ __forceinline__ unsigned int pack2(float a, float b) {
    return (unsigned int)f2b(a) | ((unsigned int)f2b(b) << 16);
}

typedef __attribute__((__ext_vector_type__(8))) __bf16 bf16x8;
typedef __attribute__((__ext_vector_type__(4))) float  f32x4;

#define N_NODES 100000
#define N_EDGES 3200000

// ---------- 1. degrees ----------
__global__ void k_degree(const int* __restrict__ src, const int* __restrict__ dst,
                         int* __restrict__ deg_s, int* __restrict__ deg_d, int E) {
    int i = blockIdx.x * blockDim.x + threadIdx.x;
    if (i < E) {
        atomicAdd(&deg_s[src[i]], 1);
        atomicAdd(&deg_d[dst[i]], 1);
    }
}

// ---------- 2. norms ----------
__global__ void k_norm(const int* __restrict__ deg_s, const int* __restrict__ deg_d,
                       float* __restrict__ out_norm, float* __restrict__ in_norm, int N) {
    int i = blockIdx.x * blockDim.x + threadIdx.x;
    if (i < N) {
        out_norm[i] = rsqrtf((float)max(deg_s[i], 1));
        in_norm[i]  = rsqrtf((float)max(deg_d[i], 1));
    }
}

// ---------- 3. exclusive scan of in-degrees (single block, 1024 threads) ----------
__global__ void k_scan(const int* __restrict__ deg, int* __restrict__ offsets, int N) {
    __shared__ int part[1024];
    int t = threadIdx.x;
    int chunk = (N + 1023) / 1024;
    int lo = t * chunk;
    int hi = min(lo + chunk, N);
    int s = 0;
    for (int i = lo; i < hi; i++) s += deg[i];
    part[t] = s;
    __syncthreads();
    for (int d = 1; d < 1024; d <<= 1) {
        int v = (t >= d) ? part[t - d] : 0;
        __syncthreads();
        part[t] += v;
        __syncthreads();
    }
    int base = (t == 0) ? 0 : part[t - 1];
    for (int i = lo; i < hi; i++) { offsets[i] = base; base += deg[i]; }
    if (t == 1023) offsets[N] = part[1023];
}

// ---------- 4. bucket edges by dst ----------
__global__ void k_bucket(const int* __restrict__ src, const int* __restrict__ dst,
                         const int* __restrict__ offsets, int* __restrict__ cursor,
                         int* __restrict__ esrc, int E) {
    int i = blockIdx.x * blockDim.x + threadIdx.x;
    if (i < E) {
        int d = dst[i];
        int pos = offsets[d] + atomicAdd(&cursor[d], 1);
        esrc[pos] = src[i];
    }
}

// ---------- 5. xs = bf16(x * out_norm), fp32 -> bf16 ----------
// one thread per 4 floats (128 feats/node, so 4-groups never straddle nodes)
__global__ void k_scale(const float4* __restrict__ x4, const float* __restrict__ out_norm,
                        uint2* __restrict__ xs, int total4) {
    int i = blockIdx.x * blockDim.x + threadIdx.x;
    if (i < total4) {
        int node = i >> 5;                 // 32 float4 per node
        float on = out_norm[node];
        float4 v = x4[i];
        uint2 o;
        o.x = pack2(v.x * on, v.y * on);
        o.y = pack2(v.z * on, v.w * on);
        xs[i] = o;
    }
}

// ---------- 6. aggregate: agg[n] = in_norm[n] * sum_{e: dst=n} feat[esrc[e]] ----------
// one wave per node, lane owns a bf16x2 feature pair (64 pairs = 128 feats)
__global__ void k_aggregate(const int* __restrict__ offsets, const int* __restrict__ esrc,
                            const unsigned int* __restrict__ feat, const float* __restrict__ in_norm,
                            unsigned int* __restrict__ out, int N) {
    int node = blockIdx.x * 4 + (threadIdx.x >> 6);
    if (node >= N) return;
    int lane = threadIdx.x & 63;
    int lo = offsets[node], hi = offsets[node + 1];
    float a0 = 0.f, a1 = 0.f;
    for (int k = lo; k < hi; k++) {
        int s = esrc[k];
        unsigned int p = feat[(size_t)s * 64 + lane];
        a0 += b2f_lo(p);
        a1 += b2f_hi(p);
    }
    float inn = in_norm[node];
    out[(size_t)node * 64 + lane] = pack2(a0 * inn, a1 * inn);
}

// ---------- 7. weight transpose + bf16 cast: wt[n*K+k] = bf16(w[k*N+n]) ----------
__global__ void k_transpose(const float* __restrict__ w, unsigned short* __restrict__ wt,
                            int K, int N) {
    int i = blockIdx.x * blockDim.x + threadIdx.x;
    if (i < K * N) {
        int k = i / N, n = i - k * N;
        wt[(size_t)n * K + k] = f2b(w[i]);
    }
}

// ---------- 8. MFMA GEMM (conv layers): C[M,128] = bf16(epi(A[M,K] @ W)) ----------
// WT[N,K] pre-transposed. block = 256 = 4 waves; wave tile 32x16; block tile 32x64.
// A-frag: row = lane&15 (+16), k = (lane>>4)*8 + j   [m120 layout]
// C/D:    col = lane&15, row = (lane>>4)*4 + reg     [m89/m91 verified]
__global__ void k_gemm(const unsigned short* __restrict__ A, const unsigned short* __restrict__ WT,
                       const float* __restrict__ bias, const float* __restrict__ row_scale,
                       unsigned short* __restrict__ C, int M, int N, int K) {
    int wv = threadIdx.x >> 6, lane = threadIdx.x & 63;
    int m = lane & 15, q = lane >> 4;
    int row0 = blockIdx.x * 32;
    int col0 = blockIdx.y * 64 + wv * 16;
    const unsigned short* a0 = A + (size_t)(row0 + m) * K + q * 8;
    const unsigned short* a1 = a0 + (size_t)16 * K;
    const unsigned short* bp = WT + (size_t)(col0 + m) * K + q * 8;
    f32x4 acc0 = {0.f, 0.f, 0.f, 0.f};
    f32x4 acc1 = {0.f, 0.f, 0.f, 0.f};
    for (int k = 0; k < K; k += 32) {
        bf16x8 bfr = *(const bf16x8*)(bp + k);
        bf16x8 af0 = *(const bf16x8*)(a0 + k);
        bf16x8 af1 = *(const bf16x8*)(a1 + k);
        acc0 = __builtin_amdgcn_mfma_f32_16x16x32_bf16(af0, bfr, acc0, 0, 0, 0);
        acc1 = __builtin_amdgcn_mfma_f32_16x16x32_bf16(af1, bfr, acc1, 0, 0, 0);
    }
    int c = col0 + m;
    float bc = bias[c];
#pragma unroll
    for (int r = 0; r < 4; r++) {
        int rr = row0 + q * 4 + r;
        float v = fmaxf(acc0[r] + bc, 0.f);               // relu (both conv layers)
        if (row_scale) v *= row_scale[rr];
        C[(size_t)rr * N + c] = f2b(v);
        int rr1 = rr + 16;
        float v1 = fmaxf(acc1[r] + bc, 0.f);
        if (row_scale) v1 *= row_scale[rr1];
        C[(size_t)rr1 * N + c] = f2b(v1);
    }
}

// ---------- 9. fused MLP: out = (relu(A@wm1+bm1)) @ wm2 + bm2, fp32 out ----------
// block = 256 (4 waves) handles 32 rows. Hidden [32,256] staged in LDS as bf16.
__global__ void k_mlp(const unsigned short* __restrict__ A,     // [M,128] bf16
                      const unsigned short* __restrict__ WT1,   // [256,128] bf16 (wm1^T)
                      const float* __restrict__ bm1,            // [256]
                      const unsigned short* __restrict__ WT2,   // [64,256] bf16 (wm2^T)
                      const float* __restrict__ bm2,            // [64]
                      float* __restrict__ out, int M) {
    __shared__ unsigned short H[32][264];   // row stride 264 shorts = 528 B (16B-mult, +16B pad)
    int wv = threadIdx.x >> 6, lane = threadIdx.x & 63;
    int m = lane & 15, q = lane >> 4;
    int row0 = blockIdx.x * 32;

    // stage 1: H = relu(A @ wm1 + bm1)
    const unsigned short* a0p = A + (size_t)(row0 + m) * 128 + q * 8;
    const unsigned short* a1p = a0p + (size_t)16 * 128;
    bf16x8 af0[4], af1[4];
#pragma unroll
    for (int s = 0; s < 4; s++) {
        af0[s] = *(const bf16x8*)(a0p + s * 32);
        af1[s] = *(const bf16x8*)(a1p + s * 32);
    }
#pragma unroll
    for (int cb = 0; cb < 4; cb++) {
        int colh = cb * 64 + wv * 16 + m;   // hidden index 0..255
        const unsigned short* bp = WT1 + (size_t)colh * 128 + q * 8;
        f32x4 acc0 = {0.f, 0.f, 0.f, 0.f};
        f32x4 acc1 = {0.f, 0.f, 0.f, 0.f};
#pragma unroll
        for (int s = 0; s < 4; s++) {
            bf16x8 bfr = *(const bf16x8*)(bp + s * 32);
            acc0 = __builtin_amdgcn_mfma_f32_16x16x32_bf16(af0[s], bfr, acc0, 0, 0, 0);
            acc1 = __builtin_amdgcn_mfma_f32_16x16x32_bf16(af1[s], bfr, acc1, 0, 0, 0);
        }
        float bc = bm1[colh];
#pragma unroll
        for (int r = 0; r < 4; r++) {
            H[q * 4 + r][colh]      = f2b(fmaxf(acc0[r] + bc, 0.f));
            H[q * 4 + r + 16][colh] = f2b(fmaxf(acc1[r] + bc, 0.f));
        }
    }
    __syncthreads();

    // stage 2: out = H @ wm2 + bm2   (K=256, cols 0..63, wave wv -> cols wv*16..+15)
    int colo = wv * 16 + m;
    const unsigned short* bp2 = WT2 + (size_t)colo * 256 + q * 8;
    f32x4 acc0 = {0.f, 0.f, 0.f, 0.f};
    f32x4 acc1 = {0.f, 0.f, 0.f, 0.f};
#pragma unroll
    for (int s = 0; s < 8; s++) {
        bf16x8 bfr  = *(const bf16x8*)(bp2 + s * 32);
        bf16x8 ha0  = *(const bf16x8*)(&H[m][s * 32 + q * 8]);
        bf16x8 ha1  = *(const bf16x8*)(&H[m + 16][s * 32 + q * 8]);
        acc0 = __builtin_amdgcn_mfma_f32_16x16x32_bf16(ha0, bfr, acc0, 0, 0, 0);
        acc1 = __builtin_amdgcn_mfma_f32_16x16x32_bf16(ha1, bfr, acc1, 0, 0, 0);
    }
    float bc = bm2[colo];
#pragma unroll
    for (int r = 0; r < 4; r++) {
        out[(size_t)(row0 + q * 4 + r) * 64 + colo]      = acc0[r] + bc;
        out[(size_t)(row0 + q * 4 + r + 16) * 64 + colo] = acc1[r] + bc;
    }
}

extern "C" void kernel_launch(void* const* d_in, const int* in_sizes, int n_in,
                              void* d_out, int out_size, void* d_ws, size_t ws_size,
                              hipStream_t stream) {
    const float* x    = (const float*)d_in[0];   // fp32 [N,128]
    const int*   src  = (const int*)d_in[1];
    const int*   dst  = (const int*)d_in[2];
    const float* w1   = (const float*)d_in[3];   // [128,128]
    const float* b1   = (const float*)d_in[4];
    const float* w2   = (const float*)d_in[5];   // [128,128]
    const float* b2   = (const float*)d_in[6];
    const float* wm1  = (const float*)d_in[7];   // [128,256]
    const float* bm1  = (const float*)d_in[8];
    const float* wm2  = (const float*)d_in[9];   // [256,64]
    const float* bm2  = (const float*)d_in[10];

    const int N = N_NODES;
    const int E = N_EDGES;

    char* p = (char*)d_ws;
    auto alloc = [&](size_t bytes) -> void* {
        void* r = (void*)p;
        p += (bytes + 255) & ~(size_t)255;
        return r;
    };
    int*   deg_s    = (int*)alloc((size_t)N * 4);
    int*   deg_d    = (int*)alloc((size_t)N * 4);
    int*   cursor   = (int*)alloc((size_t)N * 4);
    int*   offsets  = (int*)alloc((size_t)(N + 1) * 4);
    float* out_norm = (float*)alloc((size_t)N * 4);
    float* in_norm  = (float*)alloc((size_t)N * 4);
    int*   esrc     = (int*)alloc((size_t)E * 4);
    unsigned int* bufA = (unsigned int*)alloc((size_t)N * 128 * 2);  // xs, then agg2
    unsigned int* bufB = (unsigned int*)alloc((size_t)N * 128 * 2);  // agg1, then h2
    unsigned int* bufC = (unsigned int*)alloc((size_t)N * 128 * 2);  // hs1
    unsigned short* wt1  = (unsigned short*)alloc(128 * 128 * 2);
    unsigned short* wt2  = (unsigned short*)alloc(128 * 128 * 2);
    unsigned short* wtm1 = (unsigned short*)alloc(256 * 128 * 2);
    unsigned short* wtm2 = (unsigned short*)alloc(64 * 256 * 2);
    (void)ws_size; (void)n_in; (void)in_sizes; (void)out_size;

    hipMemsetAsync(deg_s, 0, (size_t)N * 4, stream);
    hipMemsetAsync(deg_d, 0, (size_t)N * 4, stream);
    hipMemsetAsync(cursor, 0, (size_t)N * 4, stream);

    const int TB = 256;
    // degrees + norms
    k_degree<<<dim3((E + TB - 1) / TB), dim3(TB), 0, stream>>>(src, dst, deg_s, deg_d, E);
    k_norm<<<dim3((N + TB - 1) / TB), dim3(TB), 0, stream>>>(deg_s, deg_d, out_norm, in_norm, N);
    // CSR by dst
    k_scan<<<dim3(1), dim3(1024), 0, stream>>>(deg_d, offsets, N);
    k_bucket<<<dim3((E + TB - 1) / TB), dim3(TB), 0, stream>>>(src, dst, offsets, cursor, esrc, E);
    // xs = bf16(x * out_norm)
    k_scale<<<dim3((N * 32 + TB - 1) / TB), dim3(TB), 0, stream>>>(
        (const float4*)x, out_norm, (uint2*)bufA, N * 32);
    // weight transposes (fp32 -> bf16)
    k_transpose<<<dim3((128 * 128 + TB - 1) / TB), dim3(TB), 0, stream>>>(w1, wt1, 128, 128);
    k_transpose<<<dim3((128 * 128 + TB - 1) / TB), dim3(TB), 0, stream>>>(w2, wt2, 128, 128);
    k_transpose<<<dim3((128 * 256 + TB - 1) / TB), dim3(TB), 0, stream>>>(wm1, wtm1, 128, 256);
    k_transpose<<<dim3((256 * 64 + TB - 1) / TB), dim3(TB), 0, stream>>>(wm2, wtm2, 256, 64);

    // conv1: aggregate (bufA -> bufB), gemm w1 + relu + fold out_norm for next gather (-> bufC)
    k_aggregate<<<dim3(N / 4), dim3(TB), 0, stream>>>(offsets, esrc, bufA, in_norm, bufB, N);
    k_gemm<<<dim3(N / 32, 2), dim3(TB), 0, stream>>>(
        (const unsigned short*)bufB, wt1, b1, out_norm, (unsigned short*)bufC, N, 128, 128);

    // conv2: aggregate (bufC -> bufA), gemm w2 + relu (-> bufB)
    k_aggregate<<<dim3(N / 4), dim3(TB), 0, stream>>>(offsets, esrc, bufC, in_norm, bufA, N);
    k_gemm<<<dim3(N / 32, 2), dim3(TB), 0, stream>>>(
        (const unsigned short*)bufA, wt2, b2, (const float*)nullptr, (unsigned short*)bufB, N, 128, 128);

    // fused MLP: bufB -> d_out (fp32)
    k_mlp<<<dim3(N / 32), dim3(TB), 0, stream>>>(
        (const unsigned short*)bufB, wtm1, bm1, wtm2, bm2, (float*)d_out, N);
}

// Round 3
// 958.318 us; speedup vs baseline: 1.4623x; 1.4623x over previous
//
#include <hip/hip_runtime.h>
#include <hip/hip_bf16.h>
#include <cstdint>

// ---------- bf16 helpers (raw ushort representation) ----------
__device__ __forceinline__ unsigned short f2b(float f) {
    union { float f; unsigned int i; } v; v.f = f;
    unsigned int i = v.i;
    unsigned int r = (i + 0x7FFFu + ((i >> 16) & 1u)) >> 16;   // RNE, finite inputs
    return (unsigned short)r;
}
__device__ __forceinline__ float b2f_lo(unsigned int p) {
    union { unsigned int i; float f; } v; v.i = p << 16; return v.f;
}
__device__ __forceinline__ float b2f_hi(unsigned int p) {
    union { unsigned int i; float f; } v; v.i = p & 0xFFFF0000u; return v.f;
}
__device__ __forceinline__ unsigned int pack2(float a, float b) {
    return (unsigned int)f2b(a) | ((unsigned int)f2b(b) << 16);
}

typedef __attribute__((__ext_vector_type__(8))) __bf16 bf16x8;
typedef __attribute__((__ext_vector_type__(4))) float  f32x4;

#define N_NODES 100000
#define N_EDGES 3200000

// ---------- 1. degrees ----------
__global__ void k_degree(const int* __restrict__ src, const int* __restrict__ dst,
                         int* __restrict__ deg_s, int* __restrict__ deg_d, int E) {
    int i = blockIdx.x * blockDim.x + threadIdx.x;
    if (i < E) {
        atomicAdd(&deg_s[src[i]], 1);
        atomicAdd(&deg_d[dst[i]], 1);
    }
}

// ---------- 2. norms ----------
__global__ void k_norm(const int* __restrict__ deg_s, const int* __restrict__ deg_d,
                       float* __restrict__ out_norm, float* __restrict__ in_norm, int N) {
    int i = blockIdx.x * blockDim.x + threadIdx.x;
    if (i < N) {
        out_norm[i] = rsqrtf((float)max(deg_s[i], 1));
        in_norm[i]  = rsqrtf((float)max(deg_d[i], 1));
    }
}

// ---------- 3. hierarchical exclusive scan: 100 blocks x 1000 elems ----------
// pass 1: per-block exclusive scan into offsets[], block totals into bsum[]
__global__ void k_scan1(const int* __restrict__ deg, int* __restrict__ offsets,
                        int* __restrict__ bsum, int N) {
    __shared__ int part[1024];
    int b = blockIdx.x, t = threadIdx.x;
    int idx = b * 1000 + t;
    int val = (t < 1000 && idx < N) ? deg[idx] : 0;
    part[t] = val;
    __syncthreads();
    for (int d = 1; d < 1024; d <<= 1) {
        int v = (t >= d) ? part[t - d] : 0;
        __syncthreads();
        part[t] += v;
        __syncthreads();
    }
    if (t < 1000 && idx < N) offsets[idx] = part[t] - val;   // exclusive within block
    if (t == 1023) bsum[b] = part[1023];
}
// pass 2: scan the 100 block sums (1 block, 128 threads)
__global__ void k_scan2(const int* __restrict__ bsum, int* __restrict__ bbase,
                        int* __restrict__ offsets, int NB, int N) {
    __shared__ int part[128];
    int t = threadIdx.x;
    int val = (t < NB) ? bsum[t] : 0;
    part[t] = val;
    __syncthreads();
    for (int d = 1; d < 128; d <<= 1) {
        int v = (t >= d) ? part[t - d] : 0;
        __syncthreads();
        part[t] += v;
        __syncthreads();
    }
    if (t < NB) bbase[t] = part[t] - val;                    // exclusive
    if (t == 127) offsets[N] = part[127];                    // grand total
}
// pass 3: add block base
__global__ void k_scan3(int* __restrict__ offsets, const int* __restrict__ bbase, int N) {
    int i = blockIdx.x * blockDim.x + threadIdx.x;
    if (i < N) offsets[i] += bbase[i / 1000];
}

// ---------- 4. bucket edges by dst ----------
__global__ void k_bucket(const int* __restrict__ src, const int* __restrict__ dst,
                         const int* __restrict__ offsets, int* __restrict__ cursor,
                         int* __restrict__ esrc, int E) {
    int i = blockIdx.x * blockDim.x + threadIdx.x;
    if (i < E) {
        int d = dst[i];
        int pos = offsets[d] + atomicAdd(&cursor[d], 1);
        esrc[pos] = src[i];
    }
}

// ---------- 5. xs = bf16(x * out_norm), fp32 -> bf16 ----------
__global__ void k_scale(const float4* __restrict__ x4, const float* __restrict__ out_norm,
                        uint2* __restrict__ xs, int total4) {
    int i = blockIdx.x * blockDim.x + threadIdx.x;
    if (i < total4) {
        int node = i >> 5;                 // 32 float4 per node
        float on = out_norm[node];
        float4 v = x4[i];
        uint2 o;
        o.x = pack2(v.x * on, v.y * on);
        o.y = pack2(v.z * on, v.w * on);
        xs[i] = o;
    }
}

// ---------- 6. aggregate: agg[n] = in_norm[n] * sum_{e: dst=n} feat[esrc[e]] ----------
// one wave per node; 4 edges processed per iteration:
//   lane = g*16 + c   (g = edge subgroup 0..3, c = 16B-chunk 0..15 of the 256B row)
// each lane loads uint4 (8 bf16 feats) -> 4 independent dwordx4 loads in flight.
// cross-group butterfly reduce (xor 16, 32) at the end.
__global__ void k_aggregate(const int* __restrict__ offsets, const int* __restrict__ esrc,
                            const uint4* __restrict__ feat, const float* __restrict__ in_norm,
                            uint4* __restrict__ out, int N) {
    int node = blockIdx.x * 4 + (threadIdx.x >> 6);
    if (node >= N) return;
    int lane = threadIdx.x & 63;
    int g = lane >> 4;      // edge subgroup
    int c = lane & 15;      // chunk within row (16 uint4 per 128-feat row)
    int lo = offsets[node], hi = offsets[node + 1];
    float a0 = 0.f, a1 = 0.f, a2 = 0.f, a3 = 0.f, a4 = 0.f, a5 = 0.f, a6 = 0.f, a7 = 0.f;
    for (int k = lo + g; k < hi; k += 4) {
        int s = esrc[k];
        uint4 p = feat[(size_t)s * 16 + c];
        a0 += b2f_lo(p.x); a1 += b2f_hi(p.x);
        a2 += b2f_lo(p.y); a3 += b2f_hi(p.y);
        a4 += b2f_lo(p.z); a5 += b2f_hi(p.z);
        a6 += b2f_lo(p.w); a7 += b2f_hi(p.w);
    }
    a0 += __shfl_xor(a0, 16, 64); a0 += __shfl_xor(a0, 32, 64);
    a1 += __shfl_xor(a1, 16, 64); a1 += __shfl_xor(a1, 32, 64);
    a2 += __shfl_xor(a2, 16, 64); a2 += __shfl_xor(a2, 32, 64);
    a3 += __shfl_xor(a3, 16, 64); a3 += __shfl_xor(a3, 32, 64);
    a4 += __shfl_xor(a4, 16, 64); a4 += __shfl_xor(a4, 32, 64);
    a5 += __shfl_xor(a5, 16, 64); a5 += __shfl_xor(a5, 32, 64);
    a6 += __shfl_xor(a6, 16, 64); a6 += __shfl_xor(a6, 32, 64);
    a7 += __shfl_xor(a7, 16, 64); a7 += __shfl_xor(a7, 32, 64);
    if (g == 0) {
        float inn = in_norm[node];
        uint4 o;
        o.x = pack2(a0 * inn, a1 * inn);
        o.y = pack2(a2 * inn, a3 * inn);
        o.z = pack2(a4 * inn, a5 * inn);
        o.w = pack2(a6 * inn, a7 * inn);
        out[(size_t)node * 16 + c] = o;
    }
}

// ---------- 7. weight transpose + bf16 cast: wt[n*K+k] = bf16(w[k*N+n]) ----------
__global__ void k_transpose(const float* __restrict__ w, unsigned short* __restrict__ wt,
                            int K, int N) {
    int i = blockIdx.x * blockDim.x + threadIdx.x;
    if (i < K * N) {
        int k = i / N, n = i - k * N;
        wt[(size_t)n * K + k] = f2b(w[i]);
    }
}

// ---------- 8. MFMA GEMM (conv layers): C[M,128] = bf16(epi(A[M,K] @ W)) ----------
// WT[N,K] pre-transposed. block = 256 = 4 waves; wave tile 32x16; block tile 32x64.
__global__ void k_gemm(const unsigned short* __restrict__ A, const unsigned short* __restrict__ WT,
                       const float* __restrict__ bias, const float* __restrict__ row_scale,
                       unsigned short* __restrict__ C, int M, int N, int K) {
    int wv = threadIdx.x >> 6, lane = threadIdx.x & 63;
    int m = lane & 15, q = lane >> 4;
    int row0 = blockIdx.x * 32;
    int col0 = blockIdx.y * 64 + wv * 16;
    const unsigned short* a0 = A + (size_t)(row0 + m) * K + q * 8;
    const unsigned short* a1 = a0 + (size_t)16 * K;
    const unsigned short* bp = WT + (size_t)(col0 + m) * K + q * 8;
    f32x4 acc0 = {0.f, 0.f, 0.f, 0.f};
    f32x4 acc1 = {0.f, 0.f, 0.f, 0.f};
    for (int k = 0; k < K; k += 32) {
        bf16x8 bfr = *(const bf16x8*)(bp + k);
        bf16x8 af0 = *(const bf16x8*)(a0 + k);
        bf16x8 af1 = *(const bf16x8*)(a1 + k);
        acc0 = __builtin_amdgcn_mfma_f32_16x16x32_bf16(af0, bfr, acc0, 0, 0, 0);
        acc1 = __builtin_amdgcn_mfma_f32_16x16x32_bf16(af1, bfr, acc1, 0, 0, 0);
    }
    int c = col0 + m;
    float bc = bias[c];
#pragma unroll
    for (int r = 0; r < 4; r++) {
        int rr = row0 + q * 4 + r;
        float v = fmaxf(acc0[r] + bc, 0.f);               // relu (both conv layers)
        if (row_scale) v *= row_scale[rr];
        C[(size_t)rr * N + c] = f2b(v);
        int rr1 = rr + 16;
        float v1 = fmaxf(acc1[r] + bc, 0.f);
        if (row_scale) v1 *= row_scale[rr1];
        C[(size_t)rr1 * N + c] = f2b(v1);
    }
}

// ---------- 9. fused MLP: out = (relu(A@wm1+bm1)) @ wm2 + bm2, fp32 out ----------
__global__ void k_mlp(const unsigned short* __restrict__ A,     // [M,128] bf16
                      const unsigned short* __restrict__ WT1,   // [256,128] bf16 (wm1^T)
                      const float* __restrict__ bm1,            // [256]
                      const unsigned short* __restrict__ WT2,   // [64,256] bf16 (wm2^T)
                      const float* __restrict__ bm2,            // [64]
                      float* __restrict__ out, int M) {
    __shared__ unsigned short H[32][264];   // +16B pad per row
    int wv = threadIdx.x >> 6, lane = threadIdx.x & 63;
    int m = lane & 15, q = lane >> 4;
    int row0 = blockIdx.x * 32;

    const unsigned short* a0p = A + (size_t)(row0 + m) * 128 + q * 8;
    const unsigned short* a1p = a0p + (size_t)16 * 128;
    bf16x8 af0[4], af1[4];
#pragma unroll
    for (int s = 0; s < 4; s++) {
        af0[s] = *(const bf16x8*)(a0p + s * 32);
        af1[s] = *(const bf16x8*)(a1p + s * 32);
    }
#pragma unroll
    for (int cb = 0; cb < 4; cb++) {
        int colh = cb * 64 + wv * 16 + m;   // hidden index 0..255
        const unsigned short* bp = WT1 + (size_t)colh * 128 + q * 8;
        f32x4 acc0 = {0.f, 0.f, 0.f, 0.f};
        f32x4 acc1 = {0.f, 0.f, 0.f, 0.f};
#pragma unroll
        for (int s = 0; s < 4; s++) {
            bf16x8 bfr = *(const bf16x8*)(bp + s * 32);
            acc0 = __builtin_amdgcn_mfma_f32_16x16x32_bf16(af0[s], bfr, acc0, 0, 0, 0);
            acc1 = __builtin_amdgcn_mfma_f32_16x16x32_bf16(af1[s], bfr, acc1, 0, 0, 0);
        }
        float bc = bm1[colh];
#pragma unroll
        for (int r = 0; r < 4; r++) {
            H[q * 4 + r][colh]      = f2b(fmaxf(acc0[r] + bc, 0.f));
            H[q * 4 + r + 16][colh] = f2b(fmaxf(acc1[r] + bc, 0.f));
        }
    }
    __syncthreads();

    int colo = wv * 16 + m;
    const unsigned short* bp2 = WT2 + (size_t)colo * 256 + q * 8;
    f32x4 acc0 = {0.f, 0.f, 0.f, 0.f};
    f32x4 acc1 = {0.f, 0.f, 0.f, 0.f};
#pragma unroll
    for (int s = 0; s < 8; s++) {
        bf16x8 bfr  = *(const bf16x8*)(bp2 + s * 32);
        bf16x8 ha0  = *(const bf16x8*)(&H[m][s * 32 + q * 8]);
        bf16x8 ha1  = *(const bf16x8*)(&H[m + 16][s * 32 + q * 8]);
        acc0 = __builtin_amdgcn_mfma_f32_16x16x32_bf16(ha0, bfr, acc0, 0, 0, 0);
        acc1 = __builtin_amdgcn_mfma_f32_16x16x32_bf16(ha1, bfr, acc1, 0, 0, 0);
    }
    float bc = bm2[colo];
#pragma unroll
    for (int r = 0; r < 4; r++) {
        out[(size_t)(row0 + q * 4 + r) * 64 + colo]      = acc0[r] + bc;
        out[(size_t)(row0 + q * 4 + r + 16) * 64 + colo] = acc1[r] + bc;
    }
}

extern "C" void kernel_launch(void* const* d_in, const int* in_sizes, int n_in,
                              void* d_out, int out_size, void* d_ws, size_t ws_size,
                              hipStream_t stream) {
    const float* x    = (const float*)d_in[0];   // fp32 [N,128]
    const int*   src  = (const int*)d_in[1];
    const int*   dst  = (const int*)d_in[2];
    const float* w1   = (const float*)d_in[3];
    const float* b1   = (const float*)d_in[4];
    const float* w2   = (const float*)d_in[5];
    const float* b2   = (const float*)d_in[6];
    const float* wm1  = (const float*)d_in[7];
    const float* bm1  = (const float*)d_in[8];
    const float* wm2  = (const float*)d_in[9];
    const float* bm2  = (const float*)d_in[10];

    const int N = N_NODES;
    const int E = N_EDGES;

    char* p = (char*)d_ws;
    auto alloc = [&](size_t bytes) -> void* {
        void* r = (void*)p;
        p += (bytes + 255) & ~(size_t)255;
        return r;
    };
    int*   deg_s    = (int*)alloc((size_t)N * 4);
    int*   deg_d    = (int*)alloc((size_t)N * 4);
    int*   cursor   = (int*)alloc((size_t)N * 4);
    int*   offsets  = (int*)alloc((size_t)(N + 1) * 4);
    int*   bsum     = (int*)alloc(128 * 4);
    int*   bbase    = (int*)alloc(128 * 4);
    float* out_norm = (float*)alloc((size_t)N * 4);
    float* in_norm  = (float*)alloc((size_t)N * 4);
    int*   esrc     = (int*)alloc((size_t)E * 4);
    unsigned int* bufA = (unsigned int*)alloc((size_t)N * 128 * 2);  // xs, then agg2
    unsigned int* bufB = (unsigned int*)alloc((size_t)N * 128 * 2);  // agg1, then h2
    unsigned int* bufC = (unsigned int*)alloc((size_t)N * 128 * 2);  // hs1
    unsigned short* wt1  = (unsigned short*)alloc(128 * 128 * 2);
    unsigned short* wt2  = (unsigned short*)alloc(128 * 128 * 2);
    unsigned short* wtm1 = (unsigned short*)alloc(256 * 128 * 2);
    unsigned short* wtm2 = (unsigned short*)alloc(64 * 256 * 2);
    (void)ws_size; (void)n_in; (void)in_sizes; (void)out_size;

    hipMemsetAsync(deg_s, 0, (size_t)N * 4, stream);
    hipMemsetAsync(deg_d, 0, (size_t)N * 4, stream);
    hipMemsetAsync(cursor, 0, (size_t)N * 4, stream);

    const int TB = 256;
    // degrees + norms
    k_degree<<<dim3((E + TB - 1) / TB), dim3(TB), 0, stream>>>(src, dst, deg_s, deg_d, E);
    k_norm<<<dim3((N + TB - 1) / TB), dim3(TB), 0, stream>>>(deg_s, deg_d, out_norm, in_norm, N);
    // CSR by dst: hierarchical scan (100 blocks x 1000)
    k_scan1<<<dim3(100), dim3(1024), 0, stream>>>(deg_d, offsets, bsum, N);
    k_scan2<<<dim3(1), dim3(128), 0, stream>>>(bsum, bbase, offsets, 100, N);
    k_scan3<<<dim3((N + TB - 1) / TB), dim3(TB), 0, stream>>>(offsets, bbase, N);
    k_bucket<<<dim3((E + TB - 1) / TB), dim3(TB), 0, stream>>>(src, dst, offsets, cursor, esrc, E);
    // xs = bf16(x * out_norm)
    k_scale<<<dim3((N * 32 + TB - 1) / TB), dim3(TB), 0, stream>>>(
        (const float4*)x, out_norm, (uint2*)bufA, N * 32);
    // weight transposes (fp32 -> bf16)
    k_transpose<<<dim3((128 * 128 + TB - 1) / TB), dim3(TB), 0, stream>>>(w1, wt1, 128, 128);
    k_transpose<<<dim3((128 * 128 + TB - 1) / TB), dim3(TB), 0, stream>>>(w2, wt2, 128, 128);
    k_transpose<<<dim3((128 * 256 + TB - 1) / TB), dim3(TB), 0, stream>>>(wm1, wtm1, 128, 256);
    k_transpose<<<dim3((256 * 64 + TB - 1) / TB), dim3(TB), 0, stream>>>(wm2, wtm2, 256, 64);

    // conv1: aggregate (bufA -> bufB), gemm w1 + relu + fold out_norm (-> bufC)
    k_aggregate<<<dim3(N / 4), dim3(TB), 0, stream>>>(
        offsets, esrc, (const uint4*)bufA, in_norm, (uint4*)bufB, N);
    k_gemm<<<dim3(N / 32, 2), dim3(TB), 0, stream>>>(
        (const unsigned short*)bufB, wt1, b1, out_norm, (unsigned short*)bufC, N, 128, 128);

    // conv2: aggregate (bufC -> bufA), gemm w2 + relu (-> bufB)
    k_aggregate<<<dim3(N / 4), dim3(TB), 0, stream>>>(
        offsets, esrc, (const uint4*)bufC, in_norm, (uint4*)bufA, N);
    k_gemm<<<dim3(N / 32, 2), dim3(TB), 0, stream>>>(
        (const unsigned short*)bufA, wt2, b2, (const float*)nullptr, (unsigned short*)bufB, N, 128, 128);

    // fused MLP: bufB -> d_out (fp32)
    k_mlp<<<dim3(N / 32), dim3(TB), 0, stream>>>(
        (const unsigned short*)bufB, wtm1, bm1, wtm2, bm2, (float*)d_out, N);
}

// Round 5
// 952.897 us; speedup vs baseline: 1.4707x; 1.0057x over previous
//
#include <hip/hip_runtime.h>
#include <hip/hip_bf16.h>
#include <cstdint>

// ---------- bf16 helpers (raw ushort representation) ----------
__device__ __forceinline__ unsigned short f2b(float f) {
    union { float f; unsigned int i; } v; v.f = f;
    unsigned int i = v.i;
    unsigned int r = (i + 0x7FFFu + ((i >> 16) & 1u)) >> 16;   // RNE, finite inputs
    return (unsigned short)r;
}
__device__ __forceinline__ float b2f_lo(unsigned int p) {
    union { unsigned int i; float f; } v; v.i = p << 16; return v.f;
}
__device__ __forceinline__ float b2f_hi(unsigned int p) {
    union { unsigned int i; float f; } v; v.i = p & 0xFFFF0000u; return v.f;
}
__device__ __forceinline__ unsigned int pack2(float a, float b) {
    return (unsigned int)f2b(a) | ((unsigned int)f2b(b) << 16);
}

typedef __attribute__((__ext_vector_type__(8))) __bf16 bf16x8;
typedef __attribute__((__ext_vector_type__(4))) float  f32x4;

#define N_NODES 100000
#define N_EDGES 3200000
#define NBUCK   200        // coarse buckets
#define BSZ     500        // nodes per bucket (200*500 = 100000)

// ---------- 1. coarse histograms (dst and src) — LDS-privatized ----------
__global__ void k_hist2(const int* __restrict__ src, const int* __restrict__ dst,
                        int* __restrict__ gcntA, int* __restrict__ gcntB, int E) {
    __shared__ int hA[NBUCK], hB[NBUCK];
    int t = threadIdx.x;
    if (t < NBUCK) { hA[t] = 0; hB[t] = 0; }
    __syncthreads();
    for (int i = blockIdx.x * blockDim.x + t; i < E; i += gridDim.x * blockDim.x) {
        atomicAdd(&hA[dst[i] / BSZ], 1);
        atomicAdd(&hB[src[i] / BSZ], 1);
    }
    __syncthreads();
    if (t < NBUCK) {
        if (hA[t]) atomicAdd(&gcntA[t], hA[t]);
        if (hB[t]) atomicAdd(&gcntB[t], hB[t]);
    }
}

// ---------- 2. scan coarse counts -> bucket bases + cursors ----------
__global__ void k_scan_coarse(const int* __restrict__ gcntA, const int* __restrict__ gcntB,
                              int* __restrict__ gbaseA, int* __restrict__ gbaseB,
                              int* __restrict__ gcurA, int* __restrict__ gcurB,
                              int* __restrict__ offsets) {
    __shared__ int pA[256], pB[256];
    int t = threadIdx.x;
    int vA = (t < NBUCK) ? gcntA[t] : 0;
    int vB = (t < NBUCK) ? gcntB[t] : 0;
    pA[t] = vA; pB[t] = vB;
    __syncthreads();
    for (int d = 1; d < 256; d <<= 1) {
        int a = (t >= d) ? pA[t - d] : 0;
        int b = (t >= d) ? pB[t - d] : 0;
        __syncthreads();
        pA[t] += a; pB[t] += b;
        __syncthreads();
    }
    if (t < NBUCK) {
        gbaseA[t] = pA[t] - vA; gcurA[t] = pA[t] - vA;
        gbaseB[t] = pB[t] - vB; gcurB[t] = pB[t] - vB;
    }
    if (t == 255) {
        gbaseA[NBUCK] = pA[255];
        gbaseB[NBUCK] = pB[255];
        offsets[N_NODES] = pA[255];   // == E
    }
}

// ---------- 3. scatter edges to coarse buckets (pairs by dst, keys by src) ----------
// all per-edge atomics are LDS; 2*NBUCK global atomics per block for reservations
__global__ void k_scatter(const int* __restrict__ src, const int* __restrict__ dst,
                          int* __restrict__ gcurA, int* __restrict__ gcurB,
                          uint2* __restrict__ pairs, int* __restrict__ keysB, int E) {
    __shared__ int hA[NBUCK], hB[NBUCK], baA[NBUCK], baB[NBUCK], lcA[NBUCK], lcB[NBUCK];
    int t = threadIdx.x;
    const int CHUNK = 12500;                       // E / 256 blocks
    int lo = blockIdx.x * CHUNK, hi = min(lo + CHUNK, E);
    if (t < NBUCK) { hA[t] = 0; hB[t] = 0; }
    __syncthreads();
    for (int i = lo + t; i < hi; i += 256) {
        atomicAdd(&hA[dst[i] / BSZ], 1);
        atomicAdd(&hB[src[i] / BSZ], 1);
    }
    __syncthreads();
    if (t < NBUCK) {
        baA[t] = hA[t] ? atomicAdd(&gcurA[t], hA[t]) : 0;
        lcA[t] = 0;
        baB[t] = hB[t] ? atomicAdd(&gcurB[t], hB[t]) : 0;
        lcB[t] = 0;
    }
    __syncthreads();
    for (int i = lo + t; i < hi; i += 256) {
        int s = src[i], d = dst[i];
        int bA = d / BSZ;
        int l  = atomicAdd(&lcA[bA], 1);
        pairs[baA[bA] + l] = make_uint2((unsigned)s, (unsigned)d);
        int bB = s / BSZ;
        int l2 = atomicAdd(&lcB[bB], 1);
        keysB[baB[bB] + l2] = s;
    }
}

// ---------- 4. per-bucket CSR finalize: offsets, in_norm, esrc ----------
__global__ void k_csr_bucket(const uint2* __restrict__ pairs, const int* __restrict__ gbaseA,
                             int* __restrict__ offsets, float* __restrict__ in_norm,
                             int* __restrict__ esrc) {
    __shared__ int hist[512], scan[512], curs[512];
    int b = blockIdx.x, t = threadIdx.x;
    int node0 = b * BSZ;
    int bstart = gbaseA[b], bend = gbaseA[b + 1];
    if (t < 512) hist[t] = 0;
    __syncthreads();
    for (int i = bstart + t; i < bend; i += 1024)
        atomicAdd(&hist[(int)pairs[i].y - node0], 1);
    __syncthreads();
    if (t < 512) scan[t] = hist[t];
    __syncthreads();
    for (int d = 1; d < 512; d <<= 1) {
        int v = (t < 512 && t >= d) ? scan[t - d] : 0;
        __syncthreads();
        if (t < 512) scan[t] += v;
        __syncthreads();
    }
    if (t < BSZ) {
        int excl = scan[t] - hist[t];
        offsets[node0 + t] = bstart + excl;
        in_norm[node0 + t] = rsqrtf((float)max(hist[t], 1));
        curs[t] = excl;
    }
    __syncthreads();
    for (int i = bstart + t; i < bend; i += 1024) {
        uint2 p = pairs[i];
        int d = (int)p.y - node0;
        int l = atomicAdd(&curs[d], 1);
        esrc[bstart + l] = (int)p.x;
    }
}

// ---------- 4b. canonicalize: sort each node's segment ascending ----------
// Makes esrc content bit-deterministic regardless of atomic arrival order
// (ties are identical values -> identical sums). One thread per node,
// insertion sort over avg-32 segments; segment spans <=2 cache lines (L1-hot).
__global__ void k_sortseg(const int* __restrict__ offsets, int* __restrict__ esrc, int N) {
    int n = blockIdx.x * blockDim.x + threadIdx.x;
    if (n >= N) return;
    int lo = offsets[n], hi = offsets[n + 1];
    for (int i = lo + 1; i < hi; i++) {
        int v = esrc[i];
        int j = i - 1;
        while (j >= lo && esrc[j] > v) { esrc[j + 1] = esrc[j]; j--; }
        esrc[j + 1] = v;
    }
}

// ---------- 5. per-bucket src count -> out_norm ----------
__global__ void k_count_bucket(const int* __restrict__ keys, const int* __restrict__ gbaseB,
                               float* __restrict__ out_norm) {
    __shared__ int hist[512];
    int b = blockIdx.x, t = threadIdx.x;
    int node0 = b * BSZ;
    int bstart = gbaseB[b], bend = gbaseB[b + 1];
    if (t < 512) hist[t] = 0;
    __syncthreads();
    for (int i = bstart + t; i < bend; i += 1024)
        atomicAdd(&hist[keys[i] - node0], 1);
    __syncthreads();
    if (t < BSZ) out_norm[node0 + t] = rsqrtf((float)max(hist[t], 1));
}

// ---------- 6. xs = bf16(x * out_norm), fp32 -> bf16 ----------
__global__ void k_scale(const float4* __restrict__ x4, const float* __restrict__ out_norm,
                        uint2* __restrict__ xs, int total4) {
    int i = blockIdx.x * blockDim.x + threadIdx.x;
    if (i < total4) {
        int node = i >> 5;                 // 32 float4 per node
        float on = out_norm[node];
        float4 v = x4[i];
        uint2 o;
        o.x = pack2(v.x * on, v.y * on);
        o.y = pack2(v.z * on, v.w * on);
        xs[i] = o;
    }
}

// ---------- 7. aggregate: agg[n] = in_norm[n] * sum_{e: dst=n} feat[esrc[e]] ----------
__global__ void k_aggregate(const int* __restrict__ offsets, const int* __restrict__ esrc,
                            const uint4* __restrict__ feat, const float* __restrict__ in_norm,
                            uint4* __restrict__ out, int N) {
    int node = blockIdx.x * 4 + (threadIdx.x >> 6);
    if (node >= N) return;
    int lane = threadIdx.x & 63;
    int g = lane >> 4;      // edge subgroup
    int c = lane & 15;      // 16B chunk within 256B row
    int lo = offsets[node], hi = offsets[node + 1];
    float a0 = 0.f, a1 = 0.f, a2 = 0.f, a3 = 0.f, a4 = 0.f, a5 = 0.f, a6 = 0.f, a7 = 0.f;
    for (int k = lo + g; k < hi; k += 4) {
        int s = esrc[k];
        uint4 p = feat[(size_t)s * 16 + c];
        a0 += b2f_lo(p.x); a1 += b2f_hi(p.x);
        a2 += b2f_lo(p.y); a3 += b2f_hi(p.y);
        a4 += b2f_lo(p.z); a5 += b2f_hi(p.z);
        a6 += b2f_lo(p.w); a7 += b2f_hi(p.w);
    }
    a0 += __shfl_xor(a0, 16, 64); a0 += __shfl_xor(a0, 32, 64);
    a1 += __shfl_xor(a1, 16, 64); a1 += __shfl_xor(a1, 32, 64);
    a2 += __shfl_xor(a2, 16, 64); a2 += __shfl_xor(a2, 32, 64);
    a3 += __shfl_xor(a3, 16, 64); a3 += __shfl_xor(a3, 32, 64);
    a4 += __shfl_xor(a4, 16, 64); a4 += __shfl_xor(a4, 32, 64);
    a5 += __shfl_xor(a5, 16, 64); a5 += __shfl_xor(a5, 32, 64);
    a6 += __shfl_xor(a6, 16, 64); a6 += __shfl_xor(a6, 32, 64);
    a7 += __shfl_xor(a7, 16, 64); a7 += __shfl_xor(a7, 32, 64);
    if (g == 0) {
        float inn = in_norm[node];
        uint4 o;
        o.x = pack2(a0 * inn, a1 * inn);
        o.y = pack2(a2 * inn, a3 * inn);
        o.z = pack2(a4 * inn, a5 * inn);
        o.w = pack2(a6 * inn, a7 * inn);
        out[(size_t)node * 16 + c] = o;
    }
}

// ---------- 8. weight transpose + bf16 cast ----------
__global__ void k_transpose(const float* __restrict__ w, unsigned short* __restrict__ wt,
                            int K, int N) {
    int i = blockIdx.x * blockDim.x + threadIdx.x;
    if (i < K * N) {
        int k = i / N, n = i - k * N;
        wt[(size_t)n * K + k] = f2b(w[i]);
    }
}

// ---------- 9. MFMA GEMM (conv layers) ----------
__global__ void k_gemm(const unsigned short* __restrict__ A, const unsigned short* __restrict__ WT,
                       const float* __restrict__ bias, const float* __restrict__ row_scale,
                       unsigned short* __restrict__ C, int M, int N, int K) {
    int wv = threadIdx.x >> 6, lane = threadIdx.x & 63;
    int m = lane & 15, q = lane >> 4;
    int row0 = blockIdx.x * 32;
    int col0 = blockIdx.y * 64 + wv * 16;
    const unsigned short* a0 = A + (size_t)(row0 + m) * K + q * 8;
    const unsigned short* a1 = a0 + (size_t)16 * K;
    const unsigned short* bp = WT + (size_t)(col0 + m) * K + q * 8;
    f32x4 acc0 = {0.f, 0.f, 0.f, 0.f};
    f32x4 acc1 = {0.f, 0.f, 0.f, 0.f};
    for (int k = 0; k < K; k += 32) {
        bf16x8 bfr = *(const bf16x8*)(bp + k);
        bf16x8 af0 = *(const bf16x8*)(a0 + k);
        bf16x8 af1 = *(const bf16x8*)(a1 + k);
        acc0 = __builtin_amdgcn_mfma_f32_16x16x32_bf16(af0, bfr, acc0, 0, 0, 0);
        acc1 = __builtin_amdgcn_mfma_f32_16x16x32_bf16(af1, bfr, acc1, 0, 0, 0);
    }
    int c = col0 + m;
    float bc = bias[c];
#pragma unroll
    for (int r = 0; r < 4; r++) {
        int rr = row0 + q * 4 + r;
        float v = fmaxf(acc0[r] + bc, 0.f);
        if (row_scale) v *= row_scale[rr];
        C[(size_t)rr * N + c] = f2b(v);
        int rr1 = rr + 16;
        float v1 = fmaxf(acc1[r] + bc, 0.f);
        if (row_scale) v1 *= row_scale[rr1];
        C[(size_t)rr1 * N + c] = f2b(v1);
    }
}

// ---------- 10. fused MLP ----------
__global__ void k_mlp(const unsigned short* __restrict__ A,
                      const unsigned short* __restrict__ WT1, const float* __restrict__ bm1,
                      const unsigned short* __restrict__ WT2, const float* __restrict__ bm2,
                      float* __restrict__ out, int M) {
    __shared__ unsigned short H[32][264];
    int wv = threadIdx.x >> 6, lane = threadIdx.x & 63;
    int m = lane & 15, q = lane >> 4;
    int row0 = blockIdx.x * 32;

    const unsigned short* a0p = A + (size_t)(row0 + m) * 128 + q * 8;
    const unsigned short* a1p = a0p + (size_t)16 * 128;
    bf16x8 af0[4], af1[4];
#pragma unroll
    for (int s = 0; s < 4; s++) {
        af0[s] = *(const bf16x8*)(a0p + s * 32);
        af1[s] = *(const bf16x8*)(a1p + s * 32);
    }
#pragma unroll
    for (int cb = 0; cb < 4; cb++) {
        int colh = cb * 64 + wv * 16 + m;
        const unsigned short* bp = WT1 + (size_t)colh * 128 + q * 8;
        f32x4 acc0 = {0.f, 0.f, 0.f, 0.f};
        f32x4 acc1 = {0.f, 0.f, 0.f, 0.f};
#pragma unroll
        for (int s = 0; s < 4; s++) {
            bf16x8 bfr = *(const bf16x8*)(bp + s * 32);
            acc0 = __builtin_amdgcn_mfma_f32_16x16x32_bf16(af0[s], bfr, acc0, 0, 0, 0);
            acc1 = __builtin_amdgcn_mfma_f32_16x16x32_bf16(af1[s], bfr, acc1, 0, 0, 0);
        }
        float bc = bm1[colh];
#pragma unroll
        for (int r = 0; r < 4; r++) {
            H[q * 4 + r][colh]      = f2b(fmaxf(acc0[r] + bc, 0.f));
            H[q * 4 + r + 16][colh] = f2b(fmaxf(acc1[r] + bc, 0.f));
        }
    }
    __syncthreads();

    int colo = wv * 16 + m;
    const unsigned short* bp2 = WT2 + (size_t)colo * 256 + q * 8;
    f32x4 acc0 = {0.f, 0.f, 0.f, 0.f};
    f32x4 acc1 = {0.f, 0.f, 0.f, 0.f};
#pragma unroll
    for (int s = 0; s < 8; s++) {
        bf16x8 bfr  = *(const bf16x8*)(bp2 + s * 32);
        bf16x8 ha0  = *(const bf16x8*)(&H[m][s * 32 + q * 8]);
        bf16x8 ha1  = *(const bf16x8*)(&H[m + 16][s * 32 + q * 8]);
        acc0 = __builtin_amdgcn_mfma_f32_16x16x32_bf16(ha0, bfr, acc0, 0, 0, 0);
        acc1 = __builtin_amdgcn_mfma_f32_16x16x32_bf16(ha1, bfr, acc1, 0, 0, 0);
    }
    float bc = bm2[colo];
#pragma unroll
    for (int r = 0; r < 4; r++) {
        out[(size_t)(row0 + q * 4 + r) * 64 + colo]      = acc0[r] + bc;
        out[(size_t)(row0 + q * 4 + r + 16) * 64 + colo] = acc1[r] + bc;
    }
}

extern "C" void kernel_launch(void* const* d_in, const int* in_sizes, int n_in,
                              void* d_out, int out_size, void* d_ws, size_t ws_size,
                              hipStream_t stream) {
    const float* x    = (const float*)d_in[0];
    const int*   src  = (const int*)d_in[1];
    const int*   dst  = (const int*)d_in[2];
    const float* w1   = (const float*)d_in[3];
    const float* b1   = (const float*)d_in[4];
    const float* w2   = (const float*)d_in[5];
    const float* b2   = (const float*)d_in[6];
    const float* wm1  = (const float*)d_in[7];
    const float* bm1  = (const float*)d_in[8];
    const float* wm2  = (const float*)d_in[9];
    const float* bm2  = (const float*)d_in[10];

    const int N = N_NODES;
    const int E = N_EDGES;

    char* p = (char*)d_ws;
    auto alloc = [&](size_t bytes) -> void* {
        void* r = (void*)p;
        p += (bytes + 255) & ~(size_t)255;
        return r;
    };
    int*   gcntA   = (int*)alloc(256 * 4);
    int*   gcntB   = (int*)alloc(256 * 4);
    int*   gbaseA  = (int*)alloc(256 * 4);
    int*   gbaseB  = (int*)alloc(256 * 4);
    int*   gcurA   = (int*)alloc(256 * 4);
    int*   gcurB   = (int*)alloc(256 * 4);
    int*   offsets = (int*)alloc((size_t)(N + 1) * 4);
    float* out_norm = (float*)alloc((size_t)N * 4);
    float* in_norm  = (float*)alloc((size_t)N * 4);
    int*   esrc     = (int*)alloc((size_t)E * 4);
    unsigned int* bufA = (unsigned int*)alloc((size_t)N * 128 * 2);  // xs, then agg2
    unsigned int* bufB = (unsigned int*)alloc((size_t)N * 128 * 2);  // pairs, agg1, h2
    unsigned int* bufC = (unsigned int*)alloc((size_t)N * 128 * 2);  // keysB, hs1
    unsigned short* wt1  = (unsigned short*)alloc(128 * 128 * 2);
    unsigned short* wt2  = (unsigned short*)alloc(128 * 128 * 2);
    unsigned short* wtm1 = (unsigned short*)alloc(256 * 128 * 2);
    unsigned short* wtm2 = (unsigned short*)alloc(64 * 256 * 2);
    (void)ws_size; (void)n_in; (void)in_sizes; (void)out_size;

    uint2* pairs = (uint2*)bufB;   // 25.6 MB, dead until agg1 output
    int*   keysB = (int*)bufC;     // 12.8 MB, dead until gemm1 output

    hipMemsetAsync(gcntA, 0, 256 * 4, stream);
    hipMemsetAsync(gcntB, 0, 256 * 4, stream);

    const int TB = 256;
    // CSR build via two-level LDS counting sort (no per-edge global atomics)
    k_hist2<<<dim3(256), dim3(TB), 0, stream>>>(src, dst, gcntA, gcntB, E);
    k_scan_coarse<<<dim3(1), dim3(TB), 0, stream>>>(gcntA, gcntB, gbaseA, gbaseB,
                                                    gcurA, gcurB, offsets);
    k_scatter<<<dim3(256), dim3(TB), 0, stream>>>(src, dst, gcurA, gcurB, pairs, keysB, E);
    k_csr_bucket<<<dim3(NBUCK), dim3(1024), 0, stream>>>(pairs, gbaseA, offsets, in_norm, esrc);
    // canonicalize segment order -> bit-deterministic sums on every launch
    k_sortseg<<<dim3((N + TB - 1) / TB), dim3(TB), 0, stream>>>(offsets, esrc, N);
    k_count_bucket<<<dim3(NBUCK), dim3(1024), 0, stream>>>(keysB, gbaseB, out_norm);

    // xs = bf16(x * out_norm)
    k_scale<<<dim3((N * 32 + TB - 1) / TB), dim3(TB), 0, stream>>>(
        (const float4*)x, out_norm, (uint2*)bufA, N * 32);
    // weight transposes (fp32 -> bf16)
    k_transpose<<<dim3((128 * 128 + TB - 1) / TB), dim3(TB), 0, stream>>>(w1, wt1, 128, 128);
    k_transpose<<<dim3((128 * 128 + TB - 1) / TB), dim3(TB), 0, stream>>>(w2, wt2, 128, 128);
    k_transpose<<<dim3((128 * 256 + TB - 1) / TB), dim3(TB), 0, stream>>>(wm1, wtm1, 128, 256);
    k_transpose<<<dim3((256 * 64 + TB - 1) / TB), dim3(TB), 0, stream>>>(wm2, wtm2, 256, 64);

    // conv1: aggregate (bufA -> bufB), gemm w1 + relu + fold out_norm (-> bufC)
    k_aggregate<<<dim3(N / 4), dim3(TB), 0, stream>>>(
        offsets, esrc, (const uint4*)bufA, in_norm, (uint4*)bufB, N);
    k_gemm<<<dim3(N / 32, 2), dim3(TB), 0, stream>>>(
        (const unsigned short*)bufB, wt1, b1, out_norm, (unsigned short*)bufC, N, 128, 128);

    // conv2: aggregate (bufC -> bufA), gemm w2 + relu (-> bufB)
    k_aggregate<<<dim3(N / 4), dim3(TB), 0, stream>>>(
        offsets, esrc, (const uint4*)bufC, in_norm, (uint4*)bufA, N);
    k_gemm<<<dim3(N / 32, 2), dim3(TB), 0, stream>>>(
        (const unsigned short*)bufA, wt2, b2, (const float*)nullptr, (unsigned short*)bufB, N, 128, 128);

    // fused MLP: bufB -> d_out (fp32)
    k_mlp<<<dim3(N / 32), dim3(TB), 0, stream>>>(
        (const unsigned short*)bufB, wtm1, bm1, wtm2, bm2, (float*)d_out, N);
}

// Round 6
// 683.173 us; speedup vs baseline: 2.0513x; 1.3948x over previous
//
#include <hip/hip_runtime.h>
#include <hip/hip_bf16.h>
#include <cstdint>

// ---------- bf16 helpers (raw ushort representation) ----------
__device__ __forceinline__ unsigned short f2b(float f) {
    union { float f; unsigned int i; } v; v.f = f;
    unsigned int i = v.i;
    unsigned int r = (i + 0x7FFFu + ((i >> 16) & 1u)) >> 16;   // RNE, finite inputs
    return (unsigned short)r;
}
__device__ __forceinline__ float b2f_lo(unsigned int p) {
    union { unsigned int i; float f; } v; v.i = p << 16; return v.f;
}
__device__ __forceinline__ float b2f_hi(unsigned int p) {
    union { unsigned int i; float f; } v; v.i = p & 0xFFFF0000u; return v.f;
}
__device__ __forceinline__ unsigned int pack2(float a, float b) {
    return (unsigned int)f2b(a) | ((unsigned int)f2b(b) << 16);
}

typedef __attribute__((__ext_vector_type__(8))) __bf16 bf16x8;
typedef __attribute__((__ext_vector_type__(4))) float  f32x4;

#define N_NODES 100000
#define N_EDGES 3200000
#define NBUCK   200        // coarse buckets
#define BSZ     500        // nodes per bucket (200*500 = 100000)

// ---------- 1. coarse histograms (dst and src) — LDS-privatized ----------
__global__ void k_hist2(const int* __restrict__ src, const int* __restrict__ dst,
                        int* __restrict__ gcntA, int* __restrict__ gcntB, int E) {
    __shared__ int hA[NBUCK], hB[NBUCK];
    int t = threadIdx.x;
    if (t < NBUCK) { hA[t] = 0; hB[t] = 0; }
    __syncthreads();
    for (int i = blockIdx.x * blockDim.x + t; i < E; i += gridDim.x * blockDim.x) {
        atomicAdd(&hA[dst[i] / BSZ], 1);
        atomicAdd(&hB[src[i] / BSZ], 1);
    }
    __syncthreads();
    if (t < NBUCK) {
        if (hA[t]) atomicAdd(&gcntA[t], hA[t]);
        if (hB[t]) atomicAdd(&gcntB[t], hB[t]);
    }
}

// ---------- 2. scan coarse counts -> bucket bases + cursors ----------
__global__ void k_scan_coarse(const int* __restrict__ gcntA, const int* __restrict__ gcntB,
                              int* __restrict__ gbaseA, int* __restrict__ gbaseB,
                              int* __restrict__ gcurA, int* __restrict__ gcurB,
                              int* __restrict__ offsets) {
    __shared__ int pA[256], pB[256];
    int t = threadIdx.x;
    int vA = (t < NBUCK) ? gcntA[t] : 0;
    int vB = (t < NBUCK) ? gcntB[t] : 0;
    pA[t] = vA; pB[t] = vB;
    __syncthreads();
    for (int d = 1; d < 256; d <<= 1) {
        int a = (t >= d) ? pA[t - d] : 0;
        int b = (t >= d) ? pB[t - d] : 0;
        __syncthreads();
        pA[t] += a; pB[t] += b;
        __syncthreads();
    }
    if (t < NBUCK) {
        gbaseA[t] = pA[t] - vA; gcurA[t] = pA[t] - vA;
        gbaseB[t] = pB[t] - vB; gcurB[t] = pB[t] - vB;
    }
    if (t == 255) {
        gbaseA[NBUCK] = pA[255];
        gbaseB[NBUCK] = pB[255];
        offsets[N_NODES] = pA[255];   // == E
    }
}

// ---------- 3. scatter edges to coarse buckets (pairs by dst, keys by src) ----------
__global__ void k_scatter(const int* __restrict__ src, const int* __restrict__ dst,
                          int* __restrict__ gcurA, int* __restrict__ gcurB,
                          uint2* __restrict__ pairs, int* __restrict__ keysB, int E) {
    __shared__ int hA[NBUCK], hB[NBUCK], baA[NBUCK], baB[NBUCK], lcA[NBUCK], lcB[NBUCK];
    int t = threadIdx.x;
    const int CHUNK = 12500;                       // E / 256 blocks
    int lo = blockIdx.x * CHUNK, hi = min(lo + CHUNK, E);
    if (t < NBUCK) { hA[t] = 0; hB[t] = 0; }
    __syncthreads();
    for (int i = lo + t; i < hi; i += 256) {
        atomicAdd(&hA[dst[i] / BSZ], 1);
        atomicAdd(&hB[src[i] / BSZ], 1);
    }
    __syncthreads();
    if (t < NBUCK) {
        baA[t] = hA[t] ? atomicAdd(&gcurA[t], hA[t]) : 0;
        lcA[t] = 0;
        baB[t] = hB[t] ? atomicAdd(&gcurB[t], hB[t]) : 0;
        lcB[t] = 0;
    }
    __syncthreads();
    for (int i = lo + t; i < hi; i += 256) {
        int s = src[i], d = dst[i];
        int bA = d / BSZ;
        int l  = atomicAdd(&lcA[bA], 1);
        pairs[baA[bA] + l] = make_uint2((unsigned)s, (unsigned)d);
        int bB = s / BSZ;
        int l2 = atomicAdd(&lcB[bB], 1);
        keysB[baB[bB] + l2] = s;
    }
}

// ---------- 4. per-bucket CSR finalize: offsets, in_norm, esrc ----------
__global__ void k_csr_bucket(const uint2* __restrict__ pairs, const int* __restrict__ gbaseA,
                             int* __restrict__ offsets, float* __restrict__ in_norm,
                             int* __restrict__ esrc) {
    __shared__ int hist[512], scan[512], curs[512];
    int b = blockIdx.x, t = threadIdx.x;
    int node0 = b * BSZ;
    int bstart = gbaseA[b], bend = gbaseA[b + 1];
    if (t < 512) hist[t] = 0;
    __syncthreads();
    for (int i = bstart + t; i < bend; i += 1024)
        atomicAdd(&hist[(int)pairs[i].y - node0], 1);
    __syncthreads();
    if (t < 512) scan[t] = hist[t];
    __syncthreads();
    for (int d = 1; d < 512; d <<= 1) {
        int v = (t < 512 && t >= d) ? scan[t - d] : 0;
        __syncthreads();
        if (t < 512) scan[t] += v;
        __syncthreads();
    }
    if (t < BSZ) {
        int excl = scan[t] - hist[t];
        offsets[node0 + t] = bstart + excl;
        in_norm[node0 + t] = rsqrtf((float)max(hist[t], 1));
        curs[t] = excl;
    }
    __syncthreads();
    for (int i = bstart + t; i < bend; i += 1024) {
        uint2 p = pairs[i];
        int d = (int)p.y - node0;
        int l = atomicAdd(&curs[d], 1);
        esrc[bstart + l] = (int)p.x;
    }
}

// ---------- 4b. canonicalize: wave-parallel bitonic sort of each segment ----------
// One wave per node; 128-element bitonic network, 2 elems/lane, INT_MAX pad.
// Equal src values are identical summands -> tie order irrelevant; sorted
// segment makes downstream sums bit-deterministic across launches.
// Degree is ~Poisson(32) here; 128 capacity is >> max degree.
__global__ void k_sortwave(const int* __restrict__ offsets, int* __restrict__ esrc, int N) {
    int node = blockIdx.x * 4 + (threadIdx.x >> 6);
    if (node >= N) return;
    int lane = threadIdx.x & 63;
    int lo = offsets[node], hi = offsets[node + 1];
    int len = hi - lo;
    if (len <= 1) return;
    const int INF = 0x7FFFFFFF;
    int v0 = (lane < len) ? esrc[lo + lane] : INF;            // virtual idx = lane
    int v1 = (64 + lane < len) ? esrc[lo + 64 + lane] : INF;  // virtual idx = 64+lane
#pragma unroll
    for (int k = 2; k <= 128; k <<= 1) {
#pragma unroll
        for (int d = 64; d > 0; d >>= 1) {
            if (d >= k) continue;                 // stages run d = k/2 .. 1
            if (d == 64) {
                int a = min(v0, v1), b = max(v0, v1);   // up: (lane & 128)==0 always
                v0 = a; v1 = b;
            } else {
                int w0 = __shfl_xor(v0, d, 64);
                int w1 = __shfl_xor(v1, d, 64);
                bool up0 = ((lane & k) == 0);           // bit6 of i0 is 0
                bool up1 = (((64 + lane) & k) == 0);
                bool lower = ((lane & d) == 0);
                v0 = (lower == up0) ? min(v0, w0) : max(v0, w0);
                v1 = (lower == up1) ? min(v1, w1) : max(v1, w1);
            }
        }
    }
    if (lane < len) esrc[lo + lane] = v0;
    if (64 + lane < len) esrc[lo + 64 + lane] = v1;
}

// ---------- 5. per-bucket src count -> out_norm ----------
__global__ void k_count_bucket(const int* __restrict__ keys, const int* __restrict__ gbaseB,
                               float* __restrict__ out_norm) {
    __shared__ int hist[512];
    int b = blockIdx.x, t = threadIdx.x;
    int node0 = b * BSZ;
    int bstart = gbaseB[b], bend = gbaseB[b + 1];
    if (t < 512) hist[t] = 0;
    __syncthreads();
    for (int i = bstart + t; i < bend; i += 1024)
        atomicAdd(&hist[keys[i] - node0], 1);
    __syncthreads();
    if (t < BSZ) out_norm[node0 + t] = rsqrtf((float)max(hist[t], 1));
}

// ---------- 6. xs = bf16(x * out_norm), fp32 -> bf16 ----------
__global__ void k_scale(const float4* __restrict__ x4, const float* __restrict__ out_norm,
                        uint2* __restrict__ xs, int total4) {
    int i = blockIdx.x * blockDim.x + threadIdx.x;
    if (i < total4) {
        int node = i >> 5;                 // 32 float4 per node
        float on = out_norm[node];
        float4 v = x4[i];
        uint2 o;
        o.x = pack2(v.x * on, v.y * on);
        o.y = pack2(v.z * on, v.w * on);
        xs[i] = o;
    }
}

// ---------- 7. aggregate: agg[n] = in_norm[n] * sum_{e: dst=n} feat[esrc[e]] ----------
__global__ void k_aggregate(const int* __restrict__ offsets, const int* __restrict__ esrc,
                            const uint4* __restrict__ feat, const float* __restrict__ in_norm,
                            uint4* __restrict__ out, int N) {
    int node = blockIdx.x * 4 + (threadIdx.x >> 6);
    if (node >= N) return;
    int lane = threadIdx.x & 63;
    int g = lane >> 4;      // edge subgroup
    int c = lane & 15;      // 16B chunk within 256B row
    int lo = offsets[node], hi = offsets[node + 1];
    float a0 = 0.f, a1 = 0.f, a2 = 0.f, a3 = 0.f, a4 = 0.f, a5 = 0.f, a6 = 0.f, a7 = 0.f;
    for (int k = lo + g; k < hi; k += 4) {
        int s = esrc[k];
        uint4 p = feat[(size_t)s * 16 + c];
        a0 += b2f_lo(p.x); a1 += b2f_hi(p.x);
        a2 += b2f_lo(p.y); a3 += b2f_hi(p.y);
        a4 += b2f_lo(p.z); a5 += b2f_hi(p.z);
        a6 += b2f_lo(p.w); a7 += b2f_hi(p.w);
    }
    a0 += __shfl_xor(a0, 16, 64); a0 += __shfl_xor(a0, 32, 64);
    a1 += __shfl_xor(a1, 16, 64); a1 += __shfl_xor(a1, 32, 64);
    a2 += __shfl_xor(a2, 16, 64); a2 += __shfl_xor(a2, 32, 64);
    a3 += __shfl_xor(a3, 16, 64); a3 += __shfl_xor(a3, 32, 64);
    a4 += __shfl_xor(a4, 16, 64); a4 += __shfl_xor(a4, 32, 64);
    a5 += __shfl_xor(a5, 16, 64); a5 += __shfl_xor(a5, 32, 64);
    a6 += __shfl_xor(a6, 16, 64); a6 += __shfl_xor(a6, 32, 64);
    a7 += __shfl_xor(a7, 16, 64); a7 += __shfl_xor(a7, 32, 64);
    if (g == 0) {
        float inn = in_norm[node];
        uint4 o;
        o.x = pack2(a0 * inn, a1 * inn);
        o.y = pack2(a2 * inn, a3 * inn);
        o.z = pack2(a4 * inn, a5 * inn);
        o.w = pack2(a6 * inn, a7 * inn);
        out[(size_t)node * 16 + c] = o;
    }
}

// ---------- 8. weight transpose + bf16 cast ----------
__global__ void k_transpose(const float* __restrict__ w, unsigned short* __restrict__ wt,
                            int K, int N) {
    int i = blockIdx.x * blockDim.x + threadIdx.x;
    if (i < K * N) {
        int k = i / N, n = i - k * N;
        wt[(size_t)n * K + k] = f2b(w[i]);
    }
}

// ---------- 9. MFMA GEMM (conv layers) ----------
__global__ void k_gemm(const unsigned short* __restrict__ A, const unsigned short* __restrict__ WT,
                       const float* __restrict__ bias, const float* __restrict__ row_scale,
                       unsigned short* __restrict__ C, int M, int N, int K) {
    int wv = threadIdx.x >> 6, lane = threadIdx.x & 63;
    int m = lane & 15, q = lane >> 4;
    int row0 = blockIdx.x * 32;
    int col0 = blockIdx.y * 64 + wv * 16;
    const unsigned short* a0 = A + (size_t)(row0 + m) * K + q * 8;
    const unsigned short* a1 = a0 + (size_t)16 * K;
    const unsigned short* bp = WT + (size_t)(col0 + m) * K + q * 8;
    f32x4 acc0 = {0.f, 0.f, 0.f, 0.f};
    f32x4 acc1 = {0.f, 0.f, 0.f, 0.f};
    for (int k = 0; k < K; k += 32) {
        bf16x8 bfr = *(const bf16x8*)(bp + k);
        bf16x8 af0 = *(const bf16x8*)(a0 + k);
        bf16x8 af1 = *(const bf16x8*)(a1 + k);
        acc0 = __builtin_amdgcn_mfma_f32_16x16x32_bf16(af0, bfr, acc0, 0, 0, 0);
        acc1 = __builtin_amdgcn_mfma_f32_16x16x32_bf16(af1, bfr, acc1, 0, 0, 0);
    }
    int c = col0 + m;
    float bc = bias[c];
#pragma unroll
    for (int r = 0; r < 4; r++) {
        int rr = row0 + q * 4 + r;
        float v = fmaxf(acc0[r] + bc, 0.f);
        if (row_scale) v *= row_scale[rr];
        C[(size_t)rr * N + c] = f2b(v);
        int rr1 = rr + 16;
        float v1 = fmaxf(acc1[r] + bc, 0.f);
        if (row_scale) v1 *= row_scale[rr1];
        C[(size_t)rr1 * N + c] = f2b(v1);
    }
}

// ---------- 10. fused MLP ----------
__global__ void k_mlp(const unsigned short* __restrict__ A,
                      const unsigned short* __restrict__ WT1, const float* __restrict__ bm1,
                      const unsigned short* __restrict__ WT2, const float* __restrict__ bm2,
                      float* __restrict__ out, int M) {
    __shared__ unsigned short H[32][264];
    int wv = threadIdx.x >> 6, lane = threadIdx.x & 63;
    int m = lane & 15, q = lane >> 4;
    int row0 = blockIdx.x * 32;

    const unsigned short* a0p = A + (size_t)(row0 + m) * 128 + q * 8;
    const unsigned short* a1p = a0p + (size_t)16 * 128;
    bf16x8 af0[4], af1[4];
#pragma unroll
    for (int s = 0; s < 4; s++) {
        af0[s] = *(const bf16x8*)(a0p + s * 32);
        af1[s] = *(const bf16x8*)(a1p + s * 32);
    }
#pragma unroll
    for (int cb = 0; cb < 4; cb++) {
        int colh = cb * 64 + wv * 16 + m;
        const unsigned short* bp = WT1 + (size_t)colh * 128 + q * 8;
        f32x4 acc0 = {0.f, 0.f, 0.f, 0.f};
        f32x4 acc1 = {0.f, 0.f, 0.f, 0.f};
#pragma unroll
        for (int s = 0; s < 4; s++) {
            bf16x8 bfr = *(const bf16x8*)(bp + s * 32);
            acc0 = __builtin_amdgcn_mfma_f32_16x16x32_bf16(af0[s], bfr, acc0, 0, 0, 0);
            acc1 = __builtin_amdgcn_mfma_f32_16x16x32_bf16(af1[s], bfr, acc1, 0, 0, 0);
        }
        float bc = bm1[colh];
#pragma unroll
        for (int r = 0; r < 4; r++) {
            H[q * 4 + r][colh]      = f2b(fmaxf(acc0[r] + bc, 0.f));
            H[q * 4 + r + 16][colh] = f2b(fmaxf(acc1[r] + bc, 0.f));
        }
    }
    __syncthreads();

    int colo = wv * 16 + m;
    const unsigned short* bp2 = WT2 + (size_t)colo * 256 + q * 8;
    f32x4 acc0 = {0.f, 0.f, 0.f, 0.f};
    f32x4 acc1 = {0.f, 0.f, 0.f, 0.f};
#pragma unroll
    for (int s = 0; s < 8; s++) {
        bf16x8 bfr  = *(const bf16x8*)(bp2 + s * 32);
        bf16x8 ha0  = *(const bf16x8*)(&H[m][s * 32 + q * 8]);
        bf16x8 ha1  = *(const bf16x8*)(&H[m + 16][s * 32 + q * 8]);
        acc0 = __builtin_amdgcn_mfma_f32_16x16x32_bf16(ha0, bfr, acc0, 0, 0, 0);
        acc1 = __builtin_amdgcn_mfma_f32_16x16x32_bf16(ha1, bfr, acc1, 0, 0, 0);
    }
    float bc = bm2[colo];
#pragma unroll
    for (int r = 0; r < 4; r++) {
        out[(size_t)(row0 + q * 4 + r) * 64 + colo]      = acc0[r] + bc;
        out[(size_t)(row0 + q * 4 + r + 16) * 64 + colo] = acc1[r] + bc;
    }
}

extern "C" void kernel_launch(void* const* d_in, const int* in_sizes, int n_in,
                              void* d_out, int out_size, void* d_ws, size_t ws_size,
                              hipStream_t stream) {
    const float* x    = (const float*)d_in[0];
    const int*   src  = (const int*)d_in[1];
    const int*   dst  = (const int*)d_in[2];
    const float* w1   = (const float*)d_in[3];
    const float* b1   = (const float*)d_in[4];
    const float* w2   = (const float*)d_in[5];
    const float* b2   = (const float*)d_in[6];
    const float* wm1  = (const float*)d_in[7];
    const float* bm1  = (const float*)d_in[8];
    const float* wm2  = (const float*)d_in[9];
    const float* bm2  = (const float*)d_in[10];

    const int N = N_NODES;
    const int E = N_EDGES;

    char* p = (char*)d_ws;
    auto alloc = [&](size_t bytes) -> void* {
        void* r = (void*)p;
        p += (bytes + 255) & ~(size_t)255;
        return r;
    };
    int*   gcntA   = (int*)alloc(256 * 4);
    int*   gcntB   = (int*)alloc(256 * 4);
    int*   gbaseA  = (int*)alloc(256 * 4);
    int*   gbaseB  = (int*)alloc(256 * 4);
    int*   gcurA   = (int*)alloc(256 * 4);
    int*   gcurB   = (int*)alloc(256 * 4);
    int*   offsets = (int*)alloc((size_t)(N + 1) * 4);
    float* out_norm = (float*)alloc((size_t)N * 4);
    float* in_norm  = (float*)alloc((size_t)N * 4);
    int*   esrc     = (int*)alloc((size_t)E * 4);
    unsigned int* bufA = (unsigned int*)alloc((size_t)N * 128 * 2);  // xs, then agg2
    unsigned int* bufB = (unsigned int*)alloc((size_t)N * 128 * 2);  // pairs, agg1, h2
    unsigned int* bufC = (unsigned int*)alloc((size_t)N * 128 * 2);  // keysB, hs1
    unsigned short* wt1  = (unsigned short*)alloc(128 * 128 * 2);
    unsigned short* wt2  = (unsigned short*)alloc(128 * 128 * 2);
    unsigned short* wtm1 = (unsigned short*)alloc(256 * 128 * 2);
    unsigned short* wtm2 = (unsigned short*)alloc(64 * 256 * 2);
    (void)ws_size; (void)n_in; (void)in_sizes; (void)out_size;

    uint2* pairs = (uint2*)bufB;   // 25.6 MB, dead until agg1 output
    int*   keysB = (int*)bufC;     // 12.8 MB, dead until gemm1 output

    hipMemsetAsync(gcntA, 0, 256 * 4, stream);
    hipMemsetAsync(gcntB, 0, 256 * 4, stream);

    const int TB = 256;
    // CSR build via two-level LDS counting sort (no per-edge global atomics)
    k_hist2<<<dim3(256), dim3(TB), 0, stream>>>(src, dst, gcntA, gcntB, E);
    k_scan_coarse<<<dim3(1), dim3(TB), 0, stream>>>(gcntA, gcntB, gbaseA, gbaseB,
                                                    gcurA, gcurB, offsets);
    k_scatter<<<dim3(256), dim3(TB), 0, stream>>>(src, dst, gcurA, gcurB, pairs, keysB, E);
    k_csr_bucket<<<dim3(NBUCK), dim3(1024), 0, stream>>>(pairs, gbaseA, offsets, in_norm, esrc);
    // canonicalize segment order (wave bitonic) -> bit-deterministic sums
    k_sortwave<<<dim3(N / 4), dim3(TB), 0, stream>>>(offsets, esrc, N);
    k_count_bucket<<<dim3(NBUCK), dim3(1024), 0, stream>>>(keysB, gbaseB, out_norm);

    // xs = bf16(x * out_norm)
    k_scale<<<dim3((N * 32 + TB - 1) / TB), dim3(TB), 0, stream>>>(
        (const float4*)x, out_norm, (uint2*)bufA, N * 32);
    // weight transposes (fp32 -> bf16)
    k_transpose<<<dim3((128 * 128 + TB - 1) / TB), dim3(TB), 0, stream>>>(w1, wt1, 128, 128);
    k_transpose<<<dim3((128 * 128 + TB - 1) / TB), dim3(TB), 0, stream>>>(w2, wt2, 128, 128);
    k_transpose<<<dim3((128 * 256 + TB - 1) / TB), dim3(TB), 0, stream>>>(wm1, wtm1, 128, 256);
    k_transpose<<<dim3((256 * 64 + TB - 1) / TB), dim3(TB), 0, stream>>>(wm2, wtm2, 256, 64);

    // conv1: aggregate (bufA -> bufB), gemm w1 + relu + fold out_norm (-> bufC)
    k_aggregate<<<dim3(N / 4), dim3(TB), 0, stream>>>(
        offsets, esrc, (const uint4*)bufA, in_norm, (uint4*)bufB, N);
    k_gemm<<<dim3(N / 32, 2), dim3(TB), 0, stream>>>(
        (const unsigned short*)bufB, wt1, b1, out_norm, (unsigned short*)bufC, N, 128, 128);

    // conv2: aggregate (bufC -> bufA), gemm w2 + relu (-> bufB)
    k_aggregate<<<dim3(N / 4), dim3(TB), 0, stream>>>(
        offsets, esrc, (const uint4*)bufC, in_norm, (uint4*)bufA, N);
    k_gemm<<<dim3(N / 32, 2), dim3(TB), 0, stream>>>(
        (const unsigned short*)bufA, wt2, b2, (const float*)nullptr, (unsigned short*)bufB, N, 128, 128);

    // fused MLP: bufB -> d_out (fp32)
    k_mlp<<<dim3(N / 32), dim3(TB), 0, stream>>>(
        (const unsigned short*)bufB, wtm1, bm1, wtm2, bm2, (float*)d_out, N);
}

// Round 8
// 667.760 us; speedup vs baseline: 2.0987x; 1.0231x over previous
//
#include <hip/hip_runtime.h>
#include <hip/hip_bf16.h>
#include <cstdint>

// ---------- bf16 helpers (raw ushort representation) ----------
__device__ __forceinline__ unsigned short f2b(float f) {
    union { float f; unsigned int i; } v; v.f = f;
    unsigned int i = v.i;
    unsigned int r = (i + 0x7FFFu + ((i >> 16) & 1u)) >> 16;   // RNE, finite inputs
    return (unsigned short)r;
}
__device__ __forceinline__ float b2f_lo(unsigned int p) {
    union { unsigned int i; float f; } v; v.i = p << 16; return v.f;
}
__device__ __forceinline__ float b2f_hi(unsigned int p) {
    union { unsigned int i; float f; } v; v.i = p & 0xFFFF0000u; return v.f;
}
__device__ __forceinline__ unsigned int pack2(float a, float b) {
    return (unsigned int)f2b(a) | ((unsigned int)f2b(b) << 16);
}

typedef __attribute__((__ext_vector_type__(8))) __bf16 bf16x8;
typedef __attribute__((__ext_vector_type__(4))) float  f32x4;

#define N_NODES 100000
#define N_EDGES 3200000
#define NBUCK   200        // coarse buckets
#define BSZ     500        // nodes per bucket (200*500 = 100000)

// ---------- 1. coarse histograms (dst and src) — LDS-privatized ----------
__global__ void k_hist2(const int* __restrict__ src, const int* __restrict__ dst,
                        int* __restrict__ gcntA, int* __restrict__ gcntB, int E) {
    __shared__ int hA[NBUCK], hB[NBUCK];
    int t = threadIdx.x;
    if (t < NBUCK) { hA[t] = 0; hB[t] = 0; }
    __syncthreads();
    for (int i = blockIdx.x * blockDim.x + t; i < E; i += gridDim.x * blockDim.x) {
        atomicAdd(&hA[dst[i] / BSZ], 1);
        atomicAdd(&hB[src[i] / BSZ], 1);
    }
    __syncthreads();
    if (t < NBUCK) {
        if (hA[t]) atomicAdd(&gcntA[t], hA[t]);
        if (hB[t]) atomicAdd(&gcntB[t], hB[t]);
    }
}

// ---------- 2. scan coarse counts -> bucket bases + cursors ----------
__global__ void k_scan_coarse(const int* __restrict__ gcntA, const int* __restrict__ gcntB,
                              int* __restrict__ gbaseA, int* __restrict__ gbaseB,
                              int* __restrict__ gcurA, int* __restrict__ gcurB,
                              int* __restrict__ offsets) {
    __shared__ int pA[256], pB[256];
    int t = threadIdx.x;
    int vA = (t < NBUCK) ? gcntA[t] : 0;
    int vB = (t < NBUCK) ? gcntB[t] : 0;
    pA[t] = vA; pB[t] = vB;
    __syncthreads();
    for (int d = 1; d < 256; d <<= 1) {
        int a = (t >= d) ? pA[t - d] : 0;
        int b = (t >= d) ? pB[t - d] : 0;
        __syncthreads();
        pA[t] += a; pB[t] += b;
        __syncthreads();
    }
    if (t < NBUCK) {
        gbaseA[t] = pA[t] - vA; gcurA[t] = pA[t] - vA;
        gbaseB[t] = pB[t] - vB; gcurB[t] = pB[t] - vB;
    }
    if (t == 255) {
        gbaseA[NBUCK] = pA[255];
        gbaseB[NBUCK] = pB[255];
        offsets[N_NODES] = pA[255];   // == E
    }
}

// ---------- 3. scatter edges to coarse buckets (pairs by dst, keys by src) ----------
__global__ void k_scatter(const int* __restrict__ src, const int* __restrict__ dst,
                          int* __restrict__ gcurA, int* __restrict__ gcurB,
                          uint2* __restrict__ pairs, int* __restrict__ keysB, int E) {
    __shared__ int hA[NBUCK], hB[NBUCK], baA[NBUCK], baB[NBUCK], lcA[NBUCK], lcB[NBUCK];
    int t = threadIdx.x;
    const int CHUNK = 12500;                       // E / 256 blocks
    int lo = blockIdx.x * CHUNK, hi = min(lo + CHUNK, E);
    if (t < NBUCK) { hA[t] = 0; hB[t] = 0; }
    __syncthreads();
    for (int i = lo + t; i < hi; i += 256) {
        atomicAdd(&hA[dst[i] / BSZ], 1);
        atomicAdd(&hB[src[i] / BSZ], 1);
    }
    __syncthreads();
    if (t < NBUCK) {
        baA[t] = hA[t] ? atomicAdd(&gcurA[t], hA[t]) : 0;
        lcA[t] = 0;
        baB[t] = hB[t] ? atomicAdd(&gcurB[t], hB[t]) : 0;
        lcB[t] = 0;
    }
    __syncthreads();
    for (int i = lo + t; i < hi; i += 256) {
        int s = src[i], d = dst[i];
        int bA = d / BSZ;
        int l  = atomicAdd(&lcA[bA], 1);
        pairs[baA[bA] + l] = make_uint2((unsigned)s, (unsigned)d);
        int bB = s / BSZ;
        int l2 = atomicAdd(&lcB[bB], 1);
        keysB[baB[bB] + l2] = s;
    }
}

// ---------- 4. per-bucket CSR finalize: offsets, in_norm, esrc ----------
__global__ void k_csr_bucket(const uint2* __restrict__ pairs, const int* __restrict__ gbaseA,
                             int* __restrict__ offsets, float* __restrict__ in_norm,
                             int* __restrict__ esrc) {
    __shared__ int hist[512], scan[512], curs[512];
    int b = blockIdx.x, t = threadIdx.x;
    int node0 = b * BSZ;
    int bstart = gbaseA[b], bend = gbaseA[b + 1];
    if (t < 512) hist[t] = 0;
    __syncthreads();
    for (int i = bstart + t; i < bend; i += 1024)
        atomicAdd(&hist[(int)pairs[i].y - node0], 1);
    __syncthreads();
    if (t < 512) scan[t] = hist[t];
    __syncthreads();
    for (int d = 1; d < 512; d <<= 1) {
        int v = (t < 512 && t >= d) ? scan[t - d] : 0;
        __syncthreads();
        if (t < 512) scan[t] += v;
        __syncthreads();
    }
    if (t < BSZ) {
        int excl = scan[t] - hist[t];
        offsets[node0 + t] = bstart + excl;
        in_norm[node0 + t] = rsqrtf((float)max(hist[t], 1));
        curs[t] = excl;
    }
    __syncthreads();
    for (int i = bstart + t; i < bend; i += 1024) {
        uint2 p = pairs[i];
        int d = (int)p.y - node0;
        int l = atomicAdd(&curs[d], 1);
        esrc[bstart + l] = (int)p.x;
    }
}

// ---------- 4b. canonicalize: wave-parallel bitonic sort of each segment ----------
__global__ void k_sortwave(const int* __restrict__ offsets, int* __restrict__ esrc, int N) {
    int node = blockIdx.x * 4 + (threadIdx.x >> 6);
    if (node >= N) return;
    int lane = threadIdx.x & 63;
    int lo = offsets[node], hi = offsets[node + 1];
    int len = hi - lo;
    if (len <= 1) return;
    const int INF = 0x7FFFFFFF;
    int v0 = (lane < len) ? esrc[lo + lane] : INF;
    int v1 = (64 + lane < len) ? esrc[lo + 64 + lane] : INF;
#pragma unroll
    for (int k = 2; k <= 128; k <<= 1) {
#pragma unroll
        for (int d = 64; d > 0; d >>= 1) {
            if (d >= k) continue;
            if (d == 64) {
                int a = min(v0, v1), b = max(v0, v1);
                v0 = a; v1 = b;
            } else {
                int w0 = __shfl_xor(v0, d, 64);
                int w1 = __shfl_xor(v1, d, 64);
                bool up0 = ((lane & k) == 0);
                bool up1 = (((64 + lane) & k) == 0);
                bool lower = ((lane & d) == 0);
                v0 = (lower == up0) ? min(v0, w0) : max(v0, w0);
                v1 = (lower == up1) ? min(v1, w1) : max(v1, w1);
            }
        }
    }
    if (lane < len) esrc[lo + lane] = v0;
    if (64 + lane < len) esrc[lo + 64 + lane] = v1;
}

// ---------- 5. per-bucket src count -> out_norm ----------
__global__ void k_count_bucket(const int* __restrict__ keys, const int* __restrict__ gbaseB,
                               float* __restrict__ out_norm) {
    __shared__ int hist[512];
    int b = blockIdx.x, t = threadIdx.x;
    int node0 = b * BSZ;
    int bstart = gbaseB[b], bend = gbaseB[b + 1];
    if (t < 512) hist[t] = 0;
    __syncthreads();
    for (int i = bstart + t; i < bend; i += 1024)
        atomicAdd(&hist[keys[i] - node0], 1);
    __syncthreads();
    if (t < BSZ) out_norm[node0 + t] = rsqrtf((float)max(hist[t], 1));
}

// ---------- 6. xs = bf16(x * out_norm), fp32 -> bf16 ----------
__global__ void k_scale(const float4* __restrict__ x4, const float* __restrict__ out_norm,
                        uint2* __restrict__ xs, int total4) {
    int i = blockIdx.x * blockDim.x + threadIdx.x;
    if (i < total4) {
        int node = i >> 5;                 // 32 float4 per node
        float on = out_norm[node];
        float4 v = x4[i];
        uint2 o;
        o.x = pack2(v.x * on, v.y * on);
        o.y = pack2(v.z * on, v.w * on);
        xs[i] = o;
    }
}

// ---------- 7. aggregate: agg[n] = in_norm[n] * sum_{e: dst=n} feat[esrc[e]] ----------
// one wave per node; lane = g*16 + c (g = edge subgroup, c = 16B chunk).
// R6 structure with manual 4x unroll: 4 independent esrc loads + 4 independent
// 16B gathers in flight per iteration; summation order identical to R6
// (ascending k within each subgroup), so results are bit-identical to R6.
__global__ void k_aggregate(const int* __restrict__ offsets, const int* __restrict__ esrc,
                            const uint4* __restrict__ feat, const float* __restrict__ in_norm,
                            uint4* __restrict__ out, int N) {
    int node = blockIdx.x * 4 + (threadIdx.x >> 6);
    if (node >= N) return;
    int lane = threadIdx.x & 63;
    int g = lane >> 4;      // edge subgroup
    int c = lane & 15;      // 16B chunk within 256B row
    int lo = offsets[node], hi = offsets[node + 1];
    float a0 = 0.f, a1 = 0.f, a2 = 0.f, a3 = 0.f, a4 = 0.f, a5 = 0.f, a6 = 0.f, a7 = 0.f;
    int k = lo + g;
    for (; k + 12 < hi; k += 16) {
        int s0 = esrc[k];
        int s1 = esrc[k + 4];
        int s2 = esrc[k + 8];
        int s3 = esrc[k + 12];
        uint4 p0 = feat[(size_t)s0 * 16 + c];
        uint4 p1 = feat[(size_t)s1 * 16 + c];
        uint4 p2 = feat[(size_t)s2 * 16 + c];
        uint4 p3 = feat[(size_t)s3 * 16 + c];
        a0 += b2f_lo(p0.x); a1 += b2f_hi(p0.x);
        a2 += b2f_lo(p0.y); a3 += b2f_hi(p0.y);
        a4 += b2f_lo(p0.z); a5 += b2f_hi(p0.z);
        a6 += b2f_lo(p0.w); a7 += b2f_hi(p0.w);
        a0 += b2f_lo(p1.x); a1 += b2f_hi(p1.x);
        a2 += b2f_lo(p1.y); a3 += b2f_hi(p1.y);
        a4 += b2f_lo(p1.z); a5 += b2f_hi(p1.z);
        a6 += b2f_lo(p1.w); a7 += b2f_hi(p1.w);
        a0 += b2f_lo(p2.x); a1 += b2f_hi(p2.x);
        a2 += b2f_lo(p2.y); a3 += b2f_hi(p2.y);
        a4 += b2f_lo(p2.z); a5 += b2f_hi(p2.z);
        a6 += b2f_lo(p2.w); a7 += b2f_hi(p2.w);
        a0 += b2f_lo(p3.x); a1 += b2f_hi(p3.x);
        a2 += b2f_lo(p3.y); a3 += b2f_hi(p3.y);
        a4 += b2f_lo(p3.z); a5 += b2f_hi(p3.z);
        a6 += b2f_lo(p3.w); a7 += b2f_hi(p3.w);
    }
    for (; k < hi; k += 4) {
        int s = esrc[k];
        uint4 p = feat[(size_t)s * 16 + c];
        a0 += b2f_lo(p.x); a1 += b2f_hi(p.x);
        a2 += b2f_lo(p.y); a3 += b2f_hi(p.y);
        a4 += b2f_lo(p.z); a5 += b2f_hi(p.z);
        a6 += b2f_lo(p.w); a7 += b2f_hi(p.w);
    }
    a0 += __shfl_xor(a0, 16, 64); a0 += __shfl_xor(a0, 32, 64);
    a1 += __shfl_xor(a1, 16, 64); a1 += __shfl_xor(a1, 32, 64);
    a2 += __shfl_xor(a2, 16, 64); a2 += __shfl_xor(a2, 32, 64);
    a3 += __shfl_xor(a3, 16, 64); a3 += __shfl_xor(a3, 32, 64);
    a4 += __shfl_xor(a4, 16, 64); a4 += __shfl_xor(a4, 32, 64);
    a5 += __shfl_xor(a5, 16, 64); a5 += __shfl_xor(a5, 32, 64);
    a6 += __shfl_xor(a6, 16, 64); a6 += __shfl_xor(a6, 32, 64);
    a7 += __shfl_xor(a7, 16, 64); a7 += __shfl_xor(a7, 32, 64);
    if (g == 0) {
        float inn = in_norm[node];
        uint4 o;
        o.x = pack2(a0 * inn, a1 * inn);
        o.y = pack2(a2 * inn, a3 * inn);
        o.z = pack2(a4 * inn, a5 * inn);
        o.w = pack2(a6 * inn, a7 * inn);
        out[(size_t)node * 16 + c] = o;
    }
}

// ---------- 8. weight transpose + bf16 cast: wt[n*K+k] = bf16(w[k*N+n]) ----------
__global__ void k_transpose(const float* __restrict__ w, unsigned short* __restrict__ wt,
                            int K, int N) {
    int i = blockIdx.x * blockDim.x + threadIdx.x;
    if (i < K * N) {
        int k = i / N, n = i - k * N;
        wt[(size_t)n * K + k] = f2b(w[i]);
    }
}

// ---------- 9. MFMA GEMM (conv layers) ----------
__global__ void k_gemm(const unsigned short* __restrict__ A, const unsigned short* __restrict__ WT,
                       const float* __restrict__ bias, const float* __restrict__ row_scale,
                       unsigned short* __restrict__ C, int M, int N, int K) {
    int wv = threadIdx.x >> 6, lane = threadIdx.x & 63;
    int m = lane & 15, q = lane >> 4;
    int row0 = blockIdx.x * 32;
    int col0 = blockIdx.y * 64 + wv * 16;
    const unsigned short* a0 = A + (size_t)(row0 + m) * K + q * 8;
    const unsigned short* a1 = a0 + (size_t)16 * K;
    const unsigned short* bp = WT + (size_t)(col0 + m) * K + q * 8;
    f32x4 acc0 = {0.f, 0.f, 0.f, 0.f};
    f32x4 acc1 = {0.f, 0.f, 0.f, 0.f};
    for (int k = 0; k < K; k += 32) {
        bf16x8 bfr = *(const bf16x8*)(bp + k);
        bf16x8 af0 = *(const bf16x8*)(a0 + k);
        bf16x8 af1 = *(const bf16x8*)(a1 + k);
        acc0 = __builtin_amdgcn_mfma_f32_16x16x32_bf16(af0, bfr, acc0, 0, 0, 0);
        acc1 = __builtin_amdgcn_mfma_f32_16x16x32_bf16(af1, bfr, acc1, 0, 0, 0);
    }
    int c = col0 + m;
    float bc = bias[c];
#pragma unroll
    for (int r = 0; r < 4; r++) {
        int rr = row0 + q * 4 + r;
        float v = fmaxf(acc0[r] + bc, 0.f);
        if (row_scale) v *= row_scale[rr];
        C[(size_t)rr * N + c] = f2b(v);
        int rr1 = rr + 16;
        float v1 = fmaxf(acc1[r] + bc, 0.f);
        if (row_scale) v1 *= row_scale[rr1];
        C[(size_t)rr1 * N + c] = f2b(v1);
    }
}

// ---------- 10. fused MLP ----------
__global__ void k_mlp(const unsigned short* __restrict__ A,
                      const unsigned short* __restrict__ WT1, const float* __restrict__ bm1,
                      const unsigned short* __restrict__ WT2, const float* __restrict__ bm2,
                      float* __restrict__ out, int M) {
    __shared__ unsigned short H[32][264];
    int wv = threadIdx.x >> 6, lane = threadIdx.x & 63;
    int m = lane & 15, q = lane >> 4;
    int row0 = blockIdx.x * 32;

    const unsigned short* a0p = A + (size_t)(row0 + m) * 128 + q * 8;
    const unsigned short* a1p = a0p + (size_t)16 * 128;
    bf16x8 af0[4], af1[4];
#pragma unroll
    for (int s = 0; s < 4; s++) {
        af0[s] = *(const bf16x8*)(a0p + s * 32);
        af1[s] = *(const bf16x8*)(a1p + s * 32);
    }
#pragma unroll
    for (int cb = 0; cb < 4; cb++) {
        int colh = cb * 64 + wv * 16 + m;
        const unsigned short* bp = WT1 + (size_t)colh * 128 + q * 8;
        f32x4 acc0 = {0.f, 0.f, 0.f, 0.f};
        f32x4 acc1 = {0.f, 0.f, 0.f, 0.f};
#pragma unroll
        for (int s = 0; s < 4; s++) {
            bf16x8 bfr = *(const bf16x8*)(bp + s * 32);
            acc0 = __builtin_amdgcn_mfma_f32_16x16x32_bf16(af0[s], bfr, acc0, 0, 0, 0);
            acc1 = __builtin_amdgcn_mfma_f32_16x16x32_bf16(af1[s], bfr, acc1, 0, 0, 0);
        }
        float bc = bm1[colh];
#pragma unroll
        for (int r = 0; r < 4; r++) {
            H[q * 4 + r][colh]      = f2b(fmaxf(acc0[r] + bc, 0.f));
            H[q * 4 + r + 16][colh] = f2b(fmaxf(acc1[r] + bc, 0.f));
        }
    }
    __syncthreads();

    int colo = wv * 16 + m;
    const unsigned short* bp2 = WT2 + (size_t)colo * 256 + q * 8;
    f32x4 acc0 = {0.f, 0.f, 0.f, 0.f};
    f32x4 acc1 = {0.f, 0.f, 0.f, 0.f};
#pragma unroll
    for (int s = 0; s < 8; s++) {
        bf16x8 bfr  = *(const bf16x8*)(bp2 + s * 32);
        bf16x8 ha0  = *(const bf16x8*)(&H[m][s * 32 + q * 8]);
        bf16x8 ha1  = *(const bf16x8*)(&H[m + 16][s * 32 + q * 8]);
        acc0 = __builtin_amdgcn_mfma_f32_16x16x32_bf16(ha0, bfr, acc0, 0, 0, 0);
        acc1 = __builtin_amdgcn_mfma_f32_16x16x32_bf16(ha1, bfr, acc1, 0, 0, 0);
    }
    float bc = bm2[colo];
#pragma unroll
    for (int r = 0; r < 4; r++) {
        out[(size_t)(row0 + q * 4 + r) * 64 + colo]      = acc0[r] + bc;
        out[(size_t)(row0 + q * 4 + r + 16) * 64 + colo] = acc1[r] + bc;
    }
}

extern "C" void kernel_launch(void* const* d_in, const int* in_sizes, int n_in,
                              void* d_out, int out_size, void* d_ws, size_t ws_size,
                              hipStream_t stream) {
    const float* x    = (const float*)d_in[0];
    const int*   src  = (const int*)d_in[1];
    const int*   dst  = (const int*)d_in[2];
    const float* w1   = (const float*)d_in[3];
    const float* b1   = (const float*)d_in[4];
    const float* w2   = (const float*)d_in[5];
    const float* b2   = (const float*)d_in[6];
    const float* wm1  = (const float*)d_in[7];
    const float* bm1  = (const float*)d_in[8];
    const float* wm2  = (const float*)d_in[9];
    const float* bm2  = (const float*)d_in[10];

    const int N = N_NODES;
    const int E = N_EDGES;

    char* p = (char*)d_ws;
    auto alloc = [&](size_t bytes) -> void* {
        void* r = (void*)p;
        p += (bytes + 255) & ~(size_t)255;
        return r;
    };
    int*   gcntA   = (int*)alloc(256 * 4);
    int*   gcntB   = (int*)alloc(256 * 4);
    int*   gbaseA  = (int*)alloc(256 * 4);
    int*   gbaseB  = (int*)alloc(256 * 4);
    int*   gcurA   = (int*)alloc(256 * 4);
    int*   gcurB   = (int*)alloc(256 * 4);
    int*   offsets = (int*)alloc((size_t)(N + 1) * 4);
    float* out_norm = (float*)alloc((size_t)N * 4);
    float* in_norm  = (float*)alloc((size_t)N * 4);
    int*   esrc     = (int*)alloc((size_t)E * 4);
    unsigned int* bufA = (unsigned int*)alloc((size_t)N * 128 * 2);  // xs, then agg2
    unsigned int* bufB = (unsigned int*)alloc((size_t)N * 128 * 2);  // pairs, agg1, h2
    unsigned int* bufC = (unsigned int*)alloc((size_t)N * 128 * 2);  // keysB, hs1
    unsigned short* wt1  = (unsigned short*)alloc(128 * 128 * 2);
    unsigned short* wt2  = (unsigned short*)alloc(128 * 128 * 2);
    unsigned short* wtm1 = (unsigned short*)alloc(256 * 128 * 2);
    unsigned short* wtm2 = (unsigned short*)alloc(64 * 256 * 2);
    (void)ws_size; (void)n_in; (void)in_sizes; (void)out_size;

    uint2* pairs = (uint2*)bufB;   // 25.6 MB, dead until agg1 output
    int*   keysB = (int*)bufC;     // 12.8 MB, dead until gemm1 output

    hipMemsetAsync(gcntA, 0, 256 * 4, stream);
    hipMemsetAsync(gcntB, 0, 256 * 4, stream);

    const int TB = 256;
    // CSR build via two-level LDS counting sort (no per-edge global atomics)
    k_hist2<<<dim3(256), dim3(TB), 0, stream>>>(src, dst, gcntA, gcntB, E);
    k_scan_coarse<<<dim3(1), dim3(TB), 0, stream>>>(gcntA, gcntB, gbaseA, gbaseB,
                                                    gcurA, gcurB, offsets);
    k_scatter<<<dim3(256), dim3(TB), 0, stream>>>(src, dst, gcurA, gcurB, pairs, keysB, E);
    k_csr_bucket<<<dim3(NBUCK), dim3(1024), 0, stream>>>(pairs, gbaseA, offsets, in_norm, esrc);
    // canonicalize segment order (wave bitonic) -> bit-deterministic sums
    k_sortwave<<<dim3(N / 4), dim3(TB), 0, stream>>>(offsets, esrc, N);
    k_count_bucket<<<dim3(NBUCK), dim3(1024), 0, stream>>>(keysB, gbaseB, out_norm);

    // xs = bf16(x * out_norm)
    k_scale<<<dim3((N * 32 + TB - 1) / TB), dim3(TB), 0, stream>>>(
        (const float4*)x, out_norm, (uint2*)bufA, N * 32);
    // weight transposes (fp32 -> bf16)
    k_transpose<<<dim3((128 * 128 + TB - 1) / TB), dim3(TB), 0, stream>>>(w1, wt1, 128, 128);
    k_transpose<<<dim3((128 * 128 + TB - 1) / TB), dim3(TB), 0, stream>>>(w2, wt2, 128, 128);
    k_transpose<<<dim3((128 * 256 + TB - 1) / TB), dim3(TB), 0, stream>>>(wm1, wtm1, 128, 256);
    k_transpose<<<dim3((256 * 64 + TB - 1) / TB), dim3(TB), 0, stream>>>(wm2, wtm2, 256, 64);

    // conv1: aggregate (bufA -> bufB), gemm w1 + relu + fold out_norm (-> bufC)
    k_aggregate<<<dim3(N / 4), dim3(TB), 0, stream>>>(
        offsets, esrc, (const uint4*)bufA, in_norm, (uint4*)bufB, N);
    k_gemm<<<dim3(N / 32, 2), dim3(TB), 0, stream>>>(
        (const unsigned short*)bufB, wt1, b1, out_norm, (unsigned short*)bufC, N, 128, 128);

    // conv2: aggregate (bufC -> bufA), gemm w2 + relu (-> bufB)
    k_aggregate<<<dim3(N / 4), dim3(TB), 0, stream>>>(
        offsets, esrc, (const uint4*)bufC, in_norm, (uint4*)bufA, N);
    k_gemm<<<dim3(N / 32, 2), dim3(TB), 0, stream>>>(
        (const unsigned short*)bufA, wt2, b2, (const float*)nullptr, (unsigned short*)bufB, N, 128, 128);

    // fused MLP: bufB -> d_out (fp32)
    k_mlp<<<dim3(N / 32), dim3(TB), 0, stream>>>(
        (const unsigned short*)bufB, wtm1, bm1, wtm2, bm2, (float*)d_out, N);
}